// Round 10
// baseline (546.322 us; speedup 1.0000x reference)
//
#include <hip/hip_runtime.h>

typedef unsigned int uint32;
typedef unsigned short u16;
typedef __attribute__((ext_vector_type(8))) short bf16x8;
typedef __attribute__((ext_vector_type(4))) float f32x4;

// ---------- helpers ----------
__device__ __forceinline__ u16 f2b(float f) {            // fp32 -> bf16 RNE
  uint32 u = __float_as_uint(f);
  u = (u + 0x7fffu + ((u >> 16) & 1u)) >> 16;
  return (u16)u;
}
__device__ __forceinline__ float b2f(u16 h) {
  return __uint_as_float(((uint32)h) << 16);
}
__device__ __forceinline__ void gl_lds16(const void* g, void* l) {
  typedef const __attribute__((address_space(1))) void* gp_t;
  typedef __attribute__((address_space(3))) void* lp_t;
  __builtin_amdgcn_global_load_lds((gp_t)g, (lp_t)l, 16, 0, 0);
}

// ---------- model constants ----------
#define L 1024
#define D 2048
#define NH 16
#define HD 128
#define VOCAB 32000
#define KV 2048
#define MASK_ID 31999

// ---------- ws layout (bytes) ----------
static constexpr long OFF_KV  = 0;                       // 2048*2048*2
static constexpr long OFF_WTQ = OFF_KV  + 8388608;
static constexpr long OFF_WTK = OFF_WTQ + 8388608;       // contiguous after WTQ (merged QKV GEMM)
static constexpr long OFF_WTV = OFF_WTK + 8388608;
static constexpr long OFF_WTO = OFF_WTV + 8388608;
static constexpr long OFF_Q   = OFF_WTO + 8388608;       // 1024*2048*2
static constexpr long OFF_K   = OFF_Q   + 4194304;       // 2048*2048*2
static constexpr long OFF_VT  = OFF_K   + 8388608;       // 2048*2048*2 (feature x token)
static constexpr long OFF_CTX = OFF_VT  + 8388608;       // 1024*2048*2
static constexpr long OFF_HID = OFF_CTX + 4194304;       // 1024*2048*2
static constexpr long OFF_LMT = OFF_HID + 4194304;       // 32000*2048*2
static constexpr long OFF_PM  = OFF_LMT + 131072000;     // 1024*128*4
static constexpr long OFF_PS  = OFF_PM  + 524288;
static constexpr long OFF_PI  = OFF_PS  + 524288;
static constexpr long OFF_PT  = OFF_PI  + 524288;        // 1024*4
static constexpr long OFF_ROW = OFF_PT  + 4096;          // 1024*2*4
static constexpr long WS_NEED = OFF_ROW + 8192;

// ---------- 128x128 transpose+convert tile body (512 threads, LDS passed in) ----------
__device__ __forceinline__ void transpose128(float* tile, const float* __restrict__ W,
                                             u16* __restrict__ WT,
                                             int Kd, int Nd, int k0, int n0) {
  int t = threadIdx.x;
  int r = t >> 2, cq = (t & 3) * 4;
#pragma unroll
  for (int p = 0; p < 8; ++p) {
    int c = cq + p * 16;
    float4 v = *(const float4*)(W + (long)(k0 + r) * Nd + n0 + c);
    float* d = tile + r * 129 + c;
    d[0] = v.x; d[1] = v.y; d[2] = v.z; d[3] = v.w;
  }
  __syncthreads();
  int q = t & 15, nn0 = t >> 4;   // nn0 0..31
#pragma unroll
  for (int p = 0; p < 4; ++p) {
    int nn = nn0 + p * 32;
    union { u16 v[8]; bf16x8 b; } u;
#pragma unroll
    for (int j = 0; j < 8; ++j) u.v[j] = f2b(tile[(q * 8 + j) * 129 + nn]);
    *(bf16x8*)(WT + (long)(n0 + nn) * Kd + k0 + q * 8) = u.b;
  }
}

// ---------- mega1: prep_kv + transpose of Wq/Wk/Wv/Wo (512 threads) ----------
__global__ __launch_bounds__(512) void mega1(const float* __restrict__ hs,
                                             const int* __restrict__ ids,
                                             const float* __restrict__ emb,
                                             u16* __restrict__ kv,
                                             const float* __restrict__ Wq, const float* __restrict__ Wk,
                                             const float* __restrict__ Wv, const float* __restrict__ Wo,
                                             u16* __restrict__ wtq, u16* __restrict__ wtk,
                                             u16* __restrict__ wtv, u16* __restrict__ wto) {
  __shared__ float tile[128 * 129];
  int bid = blockIdx.x;
  int t = threadIdx.x;
  if (bid < 512) {
    // prep: 4 rows per block
    int r = bid * 4 + (t >> 7);
    int c0 = (t & 127) * 16;
    const float* src;
    if (r < L) {
      src = hs + (long)r * D;
    } else {
      int p = r - L;
      int id = ((p & 15) == 0) ? ids[p] : MASK_ID;
      src = emb + (long)id * D;
    }
    u16* dst = kv + (long)r * D + c0;
#pragma unroll
    for (int qy = 0; qy < 2; ++qy) {
      float4 a = *(const float4*)(src + c0 + qy * 8);
      float4 b = *(const float4*)(src + c0 + qy * 8 + 4);
      ushort4 o0, o1;
      o0.x = f2b(a.x); o0.y = f2b(a.y); o0.z = f2b(a.z); o0.w = f2b(a.w);
      o1.x = f2b(b.x); o1.y = f2b(b.y); o1.z = f2b(b.z); o1.w = f2b(b.w);
      *(ushort4*)(dst + qy * 8) = o0;
      *(ushort4*)(dst + qy * 8 + 4) = o1;
    }
  } else {
    int idx = bid - 512;
    int z = idx >> 8, tt = idx & 255;
    const float* W = (z == 0) ? Wq : (z == 1) ? Wk : (z == 2) ? Wv : Wo;
    u16* T = (z == 0) ? wtq : (z == 1) ? wtk : (z == 2) ? wtv : wto;
    transpose128(tile, W, T, D, D, (tt >> 4) * 128, (tt & 15) * 128);
  }
}

// ---------- 128x128 MFMA GEMM (2-phase), A [M][K] bf16, BT [N][K] bf16 ----------
#define EPI_PLAIN 0
#define EPI_QKV 3
#define EPI_CE 4

template <int EPI>
__global__ __launch_bounds__(256) void gemm128(const u16* __restrict__ A, int lda, long aHead,
                                               const u16* __restrict__ BT, int ldb, long bHead,
                                               u16* __restrict__ C, int ldc, long cHead,
                                               int Kd) {
  __shared__ __align__(16) char lds[16384];
  char* a_lds = lds;
  char* b_lds = lds + 8192;
  int tid = threadIdx.x;
  int lane = tid & 63;
  int wave = tid >> 6;
  int wr = wave >> 1, wc = wave & 1;
  int h = blockIdx.z;
  long tm = (long)blockIdx.x * 128;
  long tn = (long)blockIdx.y * 128;
  const u16* Ap = A + (long)h * aHead + tm * lda;
  const u16* Bp = BT + (long)h * bHead + tn * ldb;

  int soff = tid * 16;
  int srow = soff >> 6;
  int scol = (soff & 63) >> 1;
  char* aldsb = a_lds + wave * 1024;
  char* bldsb = b_lds + wave * 1024;

  f32x4 acc[4][4];
#pragma unroll
  for (int i = 0; i < 4; ++i)
#pragma unroll
    for (int j = 0; j < 4; ++j) acc[i][j] = (f32x4){0.f, 0.f, 0.f, 0.f};

  for (int k0 = 0; k0 < Kd; k0 += 32) {
#pragma unroll
    for (int r = 0; r < 2; ++r) {
      gl_lds16(Ap + (long)(srow + r * 64) * lda + k0 + scol, aldsb + r * 4096);
      gl_lds16(Bp + (long)(srow + r * 64) * ldb + k0 + scol, bldsb + r * 4096);
    }
    __syncthreads();
    bf16x8 af[4], bfr[4];
    int ka = (lane >> 4) << 4;
#pragma unroll
    for (int mi = 0; mi < 4; ++mi)
      af[mi] = *(const bf16x8*)(a_lds + (wr * 64 + mi * 16 + (lane & 15)) * 64 + ka);
#pragma unroll
    for (int ni = 0; ni < 4; ++ni)
      bfr[ni] = *(const bf16x8*)(b_lds + (wc * 64 + ni * 16 + (lane & 15)) * 64 + ka);
#pragma unroll
    for (int mi = 0; mi < 4; ++mi)
#pragma unroll
      for (int ni = 0; ni < 4; ++ni)
        acc[mi][ni] = __builtin_amdgcn_mfma_f32_16x16x32_bf16(af[mi], bfr[ni], acc[mi][ni], 0, 0, 0);
    __syncthreads();
  }

  long crow0 = tm + wr * 64 + ((lane >> 4) << 2);
  int ccol0 = wc * 64 + (lane & 15);
  u16* Cp = C + (long)h * cHead;
#pragma unroll
  for (int mi = 0; mi < 4; ++mi) {
#pragma unroll
    for (int ni = 0; ni < 4; ++ni) {
      long col = tn + ccol0 + ni * 16;
#pragma unroll
      for (int j = 0; j < 4; ++j) {
        long row = crow0 + mi * 16 + j;
        Cp[row * ldc + col] = f2b(acc[mi][ni][j]);
      }
    }
  }
}

// ---------- 256x256 MFMA GEMM body: 4 merged phases per K-tile-pair ----------
// 32 MFMA per phase (full 128-row half-K), half the barriers of the 8-phase form.
// Stage cadence (slots of 16KB, 2 loads each; tile tau slots = {B_K0,A_K0,B_K1,A_K1}):
//   ph1 stages s0+7; ph2: s0+8,9 (vmcnt6 tail); ph3: s0+10,11; ph4: lgkm-drain,
//   then s0+12,13,14 (vmcnt6 tail). WAR-audited: every staged region's last reader
//   drained >= one barrier before the stage issue.
template <int EPI>
__device__ __forceinline__ void gemm256_body(char* lds, int tm, int tn,
                                             const u16* __restrict__ A, int lda,
                                             const u16* __restrict__ BT,
                                             int Kd,
                                             u16* __restrict__ Cq, u16* __restrict__ Ck,
                                             u16* __restrict__ Cv,
                                             const int* __restrict__ ids,
                                             float* __restrict__ PMAX, float* __restrict__ PSUM,
                                             int* __restrict__ PARGI, float* __restrict__ PTGT) {
  int tid = threadIdx.x, lane = tid & 63, w = tid >> 6;
  int wm = w >> 2, wn = w & 3;
  int lq = lane & 15, qq = lane >> 4;
  const char* Ap = (const char*)(A + (long)tm * 256 * lda);
  const char* Bp = (const char*)(BT + (long)tn * 256 * lda);
  int NT = Kd >> 6;             // K-tiles of 64; even, >= 2
  int maxs = NT << 2;

  // ---- hoisted addressing ----
  int swz = qq ^ ((lq >> 1) & 3);
  char* pA0 = lds + ((wm * 128 + lq) * 64 + (swz << 4));
  char* pA1 = pA0 + 65536;
  char* pB0 = lds + 32768 + ((wn * 64 + lq) * 64 + (swz << 4));
  char* pB1 = pB0 + 65536;
  int voff[2], lof[2];
#pragma unroll
  for (int l = 0; l < 2; ++l) {
    int o = tid * 16 + l * 8192;
    int rr = o >> 6;
    int ch = (o >> 4) & 3;
    int clog = ch ^ ((rr >> 1) & 3);
    voff[l] = (rr * lda + clog * 8) * 2;   // bytes into source panel
    lof[l] = w * 1024 + l * 8192;          // wave-uniform LDS dest offset
  }

  auto STAGE_SLOT = [&](int s) {
    if (s >= maxs) return;
    int tau = s >> 2, hh = s & 3;
    int kind = (hh & 1) ^ 1;    // 0 = A, 1 = B
    int ks = hh >> 1;
    const char* src = kind ? Bp : Ap;
    long kb = (long)tau * 128 + ks * 64;   // bytes
    char* dstb = lds + (tau & 1) * 65536 + kind * 32768 + ks * 16384;
#pragma unroll
    for (int l = 0; l < 2; ++l)
      gl_lds16(src + kb + voff[l], dstb + lof[l]);
  };

  f32x4 acc[8][4];
#pragma unroll
  for (int i = 0; i < 8; ++i)
#pragma unroll
    for (int j = 0; j < 4; ++j) acc[i][j] = (f32x4){0.f, 0.f, 0.f, 0.f};

  STAGE_SLOT(0); STAGE_SLOT(1); STAGE_SLOT(2); STAGE_SLOT(3);
  asm volatile("s_waitcnt vmcnt(4)" ::: "memory");
  STAGE_SLOT(4); STAGE_SLOT(5); STAGE_SLOT(6);
  asm volatile("s_waitcnt vmcnt(6)" ::: "memory");
  __builtin_amdgcn_s_barrier();
  __builtin_amdgcn_sched_barrier(0);

  bf16x8 af[8], bf0[4], bf1[4];

#define LD_AF8(PA, KS)                                                          \
  af[0] = *(const bf16x8*)((PA) + (KS) * 16384 + 0 * 1024);                     \
  af[1] = *(const bf16x8*)((PA) + (KS) * 16384 + 1 * 1024);                     \
  af[2] = *(const bf16x8*)((PA) + (KS) * 16384 + 2 * 1024);                     \
  af[3] = *(const bf16x8*)((PA) + (KS) * 16384 + 3 * 1024);                     \
  af[4] = *(const bf16x8*)((PA) + (KS) * 16384 + 4 * 1024);                     \
  af[5] = *(const bf16x8*)((PA) + (KS) * 16384 + 5 * 1024);                     \
  af[6] = *(const bf16x8*)((PA) + (KS) * 16384 + 6 * 1024);                     \
  af[7] = *(const bf16x8*)((PA) + (KS) * 16384 + 7 * 1024);
#define LD_BF(SET, PB, KS)                                                      \
  SET[0] = *(const bf16x8*)((PB) + (KS) * 16384 + 0 * 1024);                    \
  SET[1] = *(const bf16x8*)((PB) + (KS) * 16384 + 1 * 1024);                    \
  SET[2] = *(const bf16x8*)((PB) + (KS) * 16384 + 2 * 1024);                    \
  SET[3] = *(const bf16x8*)((PB) + (KS) * 16384 + 3 * 1024);
#define MFMA32(BF)                                                              \
  __builtin_amdgcn_s_setprio(1);                                                \
  _Pragma("unroll")                                                             \
  for (int mi2 = 0; mi2 < 8; ++mi2)                                             \
    _Pragma("unroll")                                                           \
    for (int ni2 = 0; ni2 < 4; ++ni2)                                           \
      acc[mi2][ni2] = __builtin_amdgcn_mfma_f32_16x16x32_bf16(                  \
          af[mi2], BF[ni2], acc[mi2][ni2], 0, 0, 0);                            \
  __builtin_amdgcn_s_setprio(0);
#define PH_SYNC                                                                 \
  __builtin_amdgcn_sched_barrier(0);                                            \
  __builtin_amdgcn_s_barrier();                                                 \
  asm volatile("s_waitcnt lgkmcnt(0)" ::: "memory");                            \
  __builtin_amdgcn_sched_barrier(0);
#define PH_TAIL(WAITV)                                                          \
  __builtin_amdgcn_sched_barrier(0);                                            \
  if ((WAITV) == 6) asm volatile("s_waitcnt vmcnt(6)" ::: "memory");            \
  else if ((WAITV) == 0) asm volatile("s_waitcnt vmcnt(0)" ::: "memory");       \
  __builtin_amdgcn_s_barrier();                                                 \
  __builtin_amdgcn_sched_barrier(0);

  for (int t = 0; t < NT; t += 2) {
    int s0 = 4 * t;
    int w4 = (t + 2 >= NT) ? 0 : 6;
    // ph1 (tile t, KS0): 32 MFMA; prefetch bf1(t) in body
    LD_BF(bf0, pB0, 0)
    LD_AF8(pA0, 0)
    STAGE_SLOT(s0 + 7);
    PH_SYNC
    LD_BF(bf1, pB0, 1)
    __builtin_amdgcn_sched_barrier(0);
    MFMA32(bf0)
    PH_TAIL(-1)
    // ph2 (tile t, KS1)
    LD_AF8(pA0, 1)
    STAGE_SLOT(s0 + 8); STAGE_SLOT(s0 + 9);
    PH_SYNC
    MFMA32(bf1)
    PH_TAIL(w4)
    // ph3 (tile t+1, KS0): prefetch bf1(t+1) in body
    LD_BF(bf0, pB1, 0)
    LD_AF8(pA1, 0)
    STAGE_SLOT(s0 + 10); STAGE_SLOT(s0 + 11);
    PH_SYNC
    LD_BF(bf1, pB1, 1)
    __builtin_amdgcn_sched_barrier(0);
    MFMA32(bf0)
    PH_TAIL(-1)
    // ph4 (tile t+1, KS1): drain bf1 prefetch reads BEFORE staging over B_K1(t+3)'s
    // aliased region readers, then stage 3 slots, then af reads (disjoint regions)
    asm volatile("s_waitcnt lgkmcnt(0)" ::: "memory");
    __builtin_amdgcn_sched_barrier(0);
    STAGE_SLOT(s0 + 12); STAGE_SLOT(s0 + 13); STAGE_SLOT(s0 + 14);
    LD_AF8(pA1, 1)
    PH_SYNC
    MFMA32(bf1)
    PH_TAIL(6)
  }
#undef LD_AF8
#undef LD_BF
#undef MFMA32
#undef PH_SYNC
#undef PH_TAIL

  if (EPI == EPI_CE) {
    __syncthreads();
    float* smax = (float*)lds;            // [256][4]
    float* ssum = smax + 1024;
    int* sargi = (int*)(ssum + 1024);
#pragma unroll
    for (int mi = 0; mi < 8; ++mi) {
#pragma unroll
      for (int j = 0; j < 4; ++j) {
        int lrow = mi * 16 + qq * 4 + j;
        long grow = (long)tm * 256 + wm * 128 + lrow;
        int tgt = ids[grow];
        float v[4];
        float mx = -1e30f; int ai = 0;
#pragma unroll
        for (int ni = 0; ni < 4; ++ni) {
          v[ni] = acc[mi][ni][j];
          int col = tn * 256 + wn * 64 + ni * 16 + lq;
          if (col == tgt) PTGT[grow] = v[ni];
          if (v[ni] > mx) { mx = v[ni]; ai = col; }
        }
#pragma unroll
        for (int off = 1; off < 16; off <<= 1) {
          float om = __shfl_xor(mx, off);
          int oa = __shfl_xor(ai, off);
          if (om > mx || (om == mx && oa < ai)) { mx = om; ai = oa; }
        }
        float se = 0.f;
#pragma unroll
        for (int ni = 0; ni < 4; ++ni) se += __expf(v[ni] - mx);
#pragma unroll
        for (int off = 1; off < 16; off <<= 1) se += __shfl_xor(se, off);
        if (lq == 0) {
          int f = wm * 128 + lrow;
          smax[f * 4 + wn] = mx;
          ssum[f * 4 + wn] = se;
          sargi[f * 4 + wn] = ai;
        }
      }
    }
    __syncthreads();
    if (lane < 32) {
      int f = w * 32 + lane;
      float m_t = smax[f * 4]; int a_t = sargi[f * 4];
#pragma unroll
      for (int x = 1; x < 4; ++x) {
        float om = smax[f * 4 + x]; int oa = sargi[f * 4 + x];
        if (om > m_t || (om == m_t && oa < a_t)) { m_t = om; a_t = oa; }
      }
      float s_t = 0.f;
#pragma unroll
      for (int x = 0; x < 4; ++x) s_t += ssum[f * 4 + x] * __expf(smax[f * 4 + x] - m_t);
      long grow = (long)tm * 256 + f;
      PMAX[grow * 128 + tn] = m_t;
      PSUM[grow * 128 + tn] = s_t;
      PARGI[grow * 128 + tn] = a_t;
    }
    return;
  }

  // EPI_QKV store
  long crow = (long)tm * 256 + wm * 128 + ((lane >> 4) << 2);
  long ccol = (long)tn * 256 + wn * 64 + lq;
#pragma unroll
  for (int mi = 0; mi < 8; ++mi)
#pragma unroll
    for (int ni = 0; ni < 4; ++ni)
#pragma unroll
      for (int j = 0; j < 4; ++j) {
        long row = crow + mi * 16 + j;
        long col = ccol + ni * 16;
        u16 val = f2b(acc[mi][ni][j]);
        if (col < 2048) {
          if (row >= 1024) Cq[(row - 1024) * D + col] = val;
        } else if (col < 4096) {
          Ck[row * D + (col - 2048)] = val;
        } else {
          Cv[(col - 4096) * KV + row] = val;
        }
      }
}

// ---------- mega2: QKV gemm256 (blocks 0..159) + lm-head transpose (blocks 160..511) ----------
__global__ __launch_bounds__(512, 2) void mega2(const u16* __restrict__ kv,
                                                const u16* __restrict__ wtq,
                                                u16* __restrict__ qb, u16* __restrict__ kb,
                                                u16* __restrict__ vt,
                                                const float* __restrict__ Wlm,
                                                u16* __restrict__ lmt) {
  __shared__ __align__(16) char lds[131072];
  int bid = blockIdx.x;
  if (bid < 160) {
    // bijective XCD swizzle over 160 (160 % 8 == 0)
    int wg = (bid & 7) * 20 + (bid >> 3);
    int tm, tn;
    if (wg < 32) { tn = wg >> 2; tm = 4 + (wg & 3); }
    else { int e = wg - 32; tn = 8 + (e >> 3); tm = e & 7; }
    gemm256_body<EPI_QKV>(lds, tm, tn, kv, D, wtq, D, qb, kb, vt,
                          nullptr, nullptr, nullptr, nullptr, nullptr);
  } else {
    for (int tile = bid - 160; tile < 4000; tile += 352) {
      int n0 = (tile % 250) * 128;
      int k0 = (tile / 250) * 128;
      transpose128((float*)lds, Wlm, lmt, D, VOCAB, k0, n0);
      __syncthreads();
    }
  }
}

// ---------- lm logits + fused CE partials ----------
__global__ __launch_bounds__(512, 2) void gemm256_ce(const u16* __restrict__ A,
                                                     const u16* __restrict__ BT,
                                                     const int* __restrict__ ids,
                                                     float* __restrict__ PMAX, float* __restrict__ PSUM,
                                                     int* __restrict__ PARGI, float* __restrict__ PTGT) {
  __shared__ __align__(16) char lds[131072];
  int nwg = gridDim.x;
  int orig = blockIdx.x;
  int q8 = nwg >> 3, r8 = nwg & 7;
  int xcd = orig & 7, idx = orig >> 3;
  int wg = (xcd < r8 ? xcd * (q8 + 1) : r8 * (q8 + 1) + (xcd - r8) * q8) + idx;
  int tm = wg / 125, tn = wg % 125;
  gemm256_body<EPI_CE>(lds, tm, tn, A, D, BT, D, nullptr, nullptr, nullptr,
                       ids, PMAX, PSUM, PARGI, PTGT);
}

// ---------- combine CE partials across 125 column tiles ----------
__global__ __launch_bounds__(256) void ce_combine(const float* __restrict__ PMAX,
                                                  const float* __restrict__ PSUM,
                                                  const int* __restrict__ PARGI,
                                                  const float* __restrict__ PTGT,
                                                  const int* __restrict__ ids,
                                                  float* __restrict__ rowbuf) {
  int row = blockIdx.x * 4 + (threadIdx.x >> 6);
  int lane = threadIdx.x & 63;
  const float* pm = PMAX + (long)row * 128;
  const float* ps = PSUM + (long)row * 128;
  const int* pi = PARGI + (long)row * 128;
  float m0 = (lane < 125) ? pm[lane] : -1e30f;
  int a0 = (lane < 125) ? pi[lane] : (1 << 30);
  float m1 = (lane + 64 < 125) ? pm[lane + 64] : -1e30f;
  int a1 = (lane + 64 < 125) ? pi[lane + 64] : (1 << 30);
  float mg = m0; int ag = a0;
  if (m1 > mg || (m1 == mg && a1 < ag)) { mg = m1; ag = a1; }
  for (int off = 1; off < 64; off <<= 1) {
    float om = __shfl_xor(mg, off);
    int oa = __shfl_xor(ag, off);
    if (om > mg || (om == mg && oa < ag)) { mg = om; ag = oa; }
  }
  float s = 0.f;
  if (lane < 125) s += ps[lane] * __expf(m0 - mg);
  if (lane + 64 < 125) s += ps[lane + 64] * __expf(m1 - mg);
  for (int off = 1; off < 64; off <<= 1) s += __shfl_xor(s, off);
  if (lane == 0) {
    rowbuf[row * 2] = mg + logf(s) - PTGT[row];
    rowbuf[row * 2 + 1] = (ag == ids[row]) ? 1.f : 0.f;
  }
}

// ---------- fused flash attention ----------
__global__ __launch_bounds__(256) void flash_attn(const u16* __restrict__ qb,
                                                  const u16* __restrict__ kb,
                                                  const u16* __restrict__ vt,
                                                  u16* __restrict__ ctx) {
  int tid = threadIdx.x;
  int lane = tid & 63;
  int wid = blockIdx.x * 4 + (tid >> 6);   // 0..1023
  int pairid = wid >> 1;
  int h = pairid >> 5;
  int pr = pairid & 31;
  int rb = (wid & 1) ? (63 - pr) : pr;     // balanced load
  int lq = lane & 15;
  int g = lane >> 4;
  const float scale = 0.08838834764831845f;  // 1/sqrt(128)

  const u16* qrow = qb + (long)(rb * 16 + lq) * D + h * HD + g * 8;
  bf16x8 qf[4];
#pragma unroll
  for (int c = 0; c < 4; ++c) qf[c] = *(const bf16x8*)(qrow + c * 32);

  f32x4 o[8];
#pragma unroll
  for (int i = 0; i < 8; ++i) o[i] = (f32x4){0.f, 0.f, 0.f, 0.f};
  float m = -1e30f, lsum = 0.f;

  int nb = rb + 1;
  for (int bp = 0; bp < nb; bp += 2) {
    bool validB = (bp + 1) < nb;
    int tokA = (bp < rb) ? bp * 16 : 1024 + rb * 16;
    int bB = bp + 1;
    int tokB = validB ? ((bB < rb) ? bB * 16 : 1024 + rb * 16) : tokA;

    f32x4 sA = (f32x4){0.f, 0.f, 0.f, 0.f};
    f32x4 sB = (f32x4){0.f, 0.f, 0.f, 0.f};
    const u16* ka = kb + (long)(tokA + lq) * D + h * HD + g * 8;
#pragma unroll
    for (int c = 0; c < 4; ++c) {
      bf16x8 kf = *(const bf16x8*)(ka + c * 32);
      sA = __builtin_amdgcn_mfma_f32_16x16x32_bf16(kf, qf[c], sA, 0, 0, 0);
    }
    if (validB) {
      const u16* kbp = kb + (long)(tokB + lq) * D + h * HD + g * 8;
#pragma unroll
      for (int c = 0; c < 4; ++c) {
        bf16x8 kf = *(const bf16x8*)(kbp + c * 32);
        sB = __builtin_amdgcn_mfma_f32_16x16x32_bf16(kf, qf[c], sB, 0, 0, 0);
      }
    }

    float s8[8];
#pragma unroll
    for (int j = 0; j < 4; ++j) s8[j] = sA[j] * scale;
#pragma unroll
    for (int j = 0; j < 4; ++j) s8[4 + j] = validB ? sB[j] * scale : -1e30f;
    float mx = s8[0];
#pragma unroll
    for (int j = 1; j < 8; ++j) mx = fmaxf(mx, s8[j]);
    mx = fmaxf(mx, __shfl_xor(mx, 16));
    mx = fmaxf(mx, __shfl_xor(mx, 32));
    float mn = fmaxf(m, mx);
    float sc_f = __expf(m - mn);
    m = mn;
    float p[8], ps = 0.f;
#pragma unroll
    for (int j = 0; j < 8; ++j) { p[j] = __expf(s8[j] - mn); ps += p[j]; }
    ps += __shfl_xor(ps, 16);
    ps += __shfl_xor(ps, 32);
    lsum = lsum * sc_f + ps;

    uint32 Aw0 = (uint32)f2b(p[0]) | ((uint32)f2b(p[1]) << 16);
    uint32 Aw1 = (uint32)f2b(p[2]) | ((uint32)f2b(p[3]) << 16);
    uint32 Bw0 = (uint32)f2b(p[4]) | ((uint32)f2b(p[5]) << 16);
    uint32 Bw1 = (uint32)f2b(p[6]) | ((uint32)f2b(p[7]) << 16);
    int s0 = (((2 * g) & 3) << 4) + lq;
    int s1 = (((2 * g + 1) & 3) << 4) + lq;
    uint32 a00 = (uint32)__shfl((int)Aw0, s0), a01 = (uint32)__shfl((int)Aw1, s0);
    uint32 a10 = (uint32)__shfl((int)Aw0, s1), a11 = (uint32)__shfl((int)Aw1, s1);
    uint32 b00 = (uint32)__shfl((int)Bw0, s0), b01 = (uint32)__shfl((int)Bw1, s0);
    uint32 b10 = (uint32)__shfl((int)Bw0, s1), b11 = (uint32)__shfl((int)Bw1, s1);
    union { uint32 u[4]; bf16x8 v; } pu;
    pu.u[0] = (g < 2) ? a00 : b00;
    pu.u[1] = (g < 2) ? a01 : b01;
    pu.u[2] = (g < 2) ? a10 : b10;
    pu.u[3] = (g < 2) ? a11 : b11;

#pragma unroll
    for (int nt = 0; nt < 8; ++nt)
#pragma unroll
      for (int j = 0; j < 4; ++j) o[nt][j] *= sc_f;
    int tok_g = (g < 2) ? (tokA + g * 8) : (tokB + (g - 2) * 8);
    const u16* vrow = vt + (long)(h * HD + lq) * KV + tok_g;
#pragma unroll
    for (int nt = 0; nt < 8; ++nt) {
      bf16x8 vf = *(const bf16x8*)(vrow + (long)nt * 16 * KV);
      o[nt] = __builtin_amdgcn_mfma_f32_16x16x32_bf16(vf, pu.v, o[nt], 0, 0, 0);
    }
  }

  float inv = 1.f / lsum;
  u16* cp = ctx + (long)(rb * 16 + lq) * D + h * HD + g * 4;
#pragma unroll
  for (int nt = 0; nt < 8; ++nt) {
    ushort4 st;
    st.x = f2b(o[nt][0] * inv); st.y = f2b(o[nt][1] * inv);
    st.z = f2b(o[nt][2] * inv); st.w = f2b(o[nt][3] * inv);
    *(ushort4*)(cp + nt * 16) = st;
  }
}

// ---------- final: masked mean loss + accuracy ----------
__global__ __launch_bounds__(256) void final_reduce(const float* __restrict__ rowbuf,
                                                    const float* __restrict__ loss_mask,
                                                    float* __restrict__ out) {
  int t = threadIdx.x;
  float ce = 0.f, cnt = 0.f, cor = 0.f;
  for (int r = t; r < L; r += 256) {
    bool valid = (r >= 16) && ((r & 15) != 0);
    float comb = loss_mask[r] * (valid ? 1.f : 0.f);
    if (comb > 1e-6f) {
      ce += rowbuf[r * 2];
      cor += rowbuf[r * 2 + 1];
      cnt += 1.f;
    }
  }
  for (int off = 1; off < 64; off <<= 1) {
    ce += __shfl_xor(ce, off);
    cnt += __shfl_xor(cnt, off);
    cor += __shfl_xor(cor, off);
  }
  __shared__ float s1[4], s2[4], s3[4];
  int lane = t & 63, w = t >> 6;
  if (lane == 0) { s1[w] = ce; s2[w] = cnt; s3[w] = cor; }
  __syncthreads();
  if (t == 0) {
    float C = s1[0] + s1[1] + s1[2] + s1[3];
    float N = s2[0] + s2[1] + s2[2] + s2[3];
    float R = s3[0] + s3[1] + s3[2] + s3[3];
    out[0] = C / N;
    out[1] = R / N;
  }
}

__global__ void ws_too_small(float* out, float mb) {
  if (threadIdx.x == 0) { out[0] = 1e6f + mb; out[1] = -1e6f; }
}

// ---------- launch ----------
extern "C" void kernel_launch(void* const* d_in, const int* in_sizes, int n_in,
                              void* d_out, int out_size, void* d_ws, size_t ws_size,
                              hipStream_t stream) {
  const int* ids = (const int*)d_in[0];
  const float* hs = (const float*)d_in[2];
  const float* lmask = (const float*)d_in[3];
  const float* emb = (const float*)d_in[4];
  const float* Wq = (const float*)d_in[5];
  const float* Wk = (const float*)d_in[6];
  const float* Wv = (const float*)d_in[7];
  const float* Wo = (const float*)d_in[8];
  const float* Wlm = (const float*)d_in[9];
  float* out = (float*)d_out;
  char* ws = (char*)d_ws;

  if (ws_size < (size_t)WS_NEED) {
    ws_too_small<<<1, 64, 0, stream>>>(out, (float)(ws_size >> 20));
    return;
  }

  u16* kv  = (u16*)(ws + OFF_KV);
  u16* wtq = (u16*)(ws + OFF_WTQ);
  u16* wtk = (u16*)(ws + OFF_WTK);
  u16* wtv = (u16*)(ws + OFF_WTV);
  u16* wto = (u16*)(ws + OFF_WTO);
  u16* qb  = (u16*)(ws + OFF_Q);
  u16* kb  = (u16*)(ws + OFF_K);
  u16* vt  = (u16*)(ws + OFF_VT);
  u16* ctx = (u16*)(ws + OFF_CTX);
  u16* hid = (u16*)(ws + OFF_HID);
  u16* lmt = (u16*)(ws + OFF_LMT);
  float* PMAX = (float*)(ws + OFF_PM);
  float* PSUM = (float*)(ws + OFF_PS);
  int* PARGI = (int*)(ws + OFF_PI);
  float* PTGT = (float*)(ws + OFF_PT);
  float* rowbuf = (float*)(ws + OFF_ROW);

  // prep kv + transpose Wq/Wk/Wv/Wo
  mega1<<<dim3(1536), 512, 0, stream>>>(hs, ids, emb, kv, Wq, Wk, Wv, Wo,
                                        wtq, wtk, wtv, wto);
  // QKV projection (256^2, 4 merged phases) overlapped with lm-head transpose
  mega2<<<dim3(512), 512, 0, stream>>>(kv, wtq, qb, kb, vt, Wlm, lmt);

  // fused block-masked flash attention -> ctx
  flash_attn<<<dim3(256), 256, 0, stream>>>(qb, kb, vt, ctx);

  // hidden = ctx @ Wo
  gemm128<EPI_PLAIN><<<dim3(8, 16, 1), 256, 0, stream>>>(ctx, D, 0, wto, D, 0, hid, D, 0, D);

  // logits + fused CE partials (no logit materialization)
  gemm256_ce<<<dim3(500), 512, 0, stream>>>(hid, lmt, ids, PMAX, PSUM, PARGI, PTGT);

  ce_combine<<<256, 256, 0, stream>>>(PMAX, PSUM, PARGI, PTGT, ids, rowbuf);
  final_reduce<<<1, 256, 0, stream>>>(rowbuf, lmask, out);
}

// Round 11
// 513.451 us; speedup vs baseline: 1.0640x; 1.0640x over previous
//
#include <hip/hip_runtime.h>

typedef unsigned int uint32;
typedef unsigned short u16;
typedef __attribute__((ext_vector_type(8))) short bf16x8;
typedef __attribute__((ext_vector_type(4))) float f32x4;

// ---------- helpers ----------
__device__ __forceinline__ u16 f2b(float f) {            // fp32 -> bf16 RNE
  uint32 u = __float_as_uint(f);
  u = (u + 0x7fffu + ((u >> 16) & 1u)) >> 16;
  return (u16)u;
}
__device__ __forceinline__ float b2f(u16 h) {
  return __uint_as_float(((uint32)h) << 16);
}
__device__ __forceinline__ void gl_lds16(const void* g, void* l) {
  typedef const __attribute__((address_space(1))) void* gp_t;
  typedef __attribute__((address_space(3))) void* lp_t;
  __builtin_amdgcn_global_load_lds((gp_t)g, (lp_t)l, 16, 0, 0);
}

// ---------- model constants ----------
#define L 1024
#define D 2048
#define NH 16
#define HD 128
#define VOCAB 32000
#define KV 2048
#define MASK_ID 31999

// ---------- ws layout (bytes) ----------
static constexpr long OFF_KV  = 0;                       // 2048*2048*2
static constexpr long OFF_WTQ = OFF_KV  + 8388608;
static constexpr long OFF_WTK = OFF_WTQ + 8388608;       // contiguous after WTQ (merged QKV GEMM)
static constexpr long OFF_WTV = OFF_WTK + 8388608;
static constexpr long OFF_WTO = OFF_WTV + 8388608;
static constexpr long OFF_Q   = OFF_WTO + 8388608;       // 1024*2048*2
static constexpr long OFF_K   = OFF_Q   + 4194304;       // 2048*2048*2
static constexpr long OFF_VT  = OFF_K   + 8388608;       // 2048*2048*2 (feature x token)
static constexpr long OFF_CTX = OFF_VT  + 8388608;       // 1024*2048*2
static constexpr long OFF_HID = OFF_CTX + 4194304;       // 1024*2048*2
static constexpr long OFF_LMT = OFF_HID + 4194304;       // 32000*2048*2
static constexpr long OFF_PM  = OFF_LMT + 131072000;     // 1024*256*4 (row-max partials, stride 256)
static constexpr long OFF_PS  = OFF_PM  + 1048576;       // 1024*256*4
static constexpr long OFF_PI  = OFF_PS  + 1048576;       // 1024*256*4
static constexpr long OFF_PT  = OFF_PI  + 1048576;       // 1024*4
static constexpr long OFF_ROW = OFF_PT  + 4096;          // 1024*2*4
static constexpr long WS_NEED = OFF_ROW + 8192;

// ---------- 128x128 transpose+convert tile body (512 threads, LDS passed in) ----------
__device__ __forceinline__ void transpose128(float* tile, const float* __restrict__ W,
                                             u16* __restrict__ WT,
                                             int Kd, int Nd, int k0, int n0) {
  int t = threadIdx.x;
  int r = t >> 2, cq = (t & 3) * 4;
#pragma unroll
  for (int p = 0; p < 8; ++p) {
    int c = cq + p * 16;
    float4 v = *(const float4*)(W + (long)(k0 + r) * Nd + n0 + c);
    float* d = tile + r * 129 + c;
    d[0] = v.x; d[1] = v.y; d[2] = v.z; d[3] = v.w;
  }
  __syncthreads();
  int q = t & 15, nn0 = t >> 4;   // nn0 0..31
#pragma unroll
  for (int p = 0; p < 4; ++p) {
    int nn = nn0 + p * 32;
    union { u16 v[8]; bf16x8 b; } u;
#pragma unroll
    for (int j = 0; j < 8; ++j) u.v[j] = f2b(tile[(q * 8 + j) * 129 + nn]);
    *(bf16x8*)(WT + (long)(n0 + nn) * Kd + k0 + q * 8) = u.b;
  }
}

// ---------- mega1: prep_kv + transpose of Wq/Wk/Wv/Wo (512 threads) ----------
__global__ __launch_bounds__(512) void mega1(const float* __restrict__ hs,
                                             const int* __restrict__ ids,
                                             const float* __restrict__ emb,
                                             u16* __restrict__ kv,
                                             const float* __restrict__ Wq, const float* __restrict__ Wk,
                                             const float* __restrict__ Wv, const float* __restrict__ Wo,
                                             u16* __restrict__ wtq, u16* __restrict__ wtk,
                                             u16* __restrict__ wtv, u16* __restrict__ wto) {
  __shared__ float tile[128 * 129];
  int bid = blockIdx.x;
  int t = threadIdx.x;
  if (bid < 512) {
    int r = bid * 4 + (t >> 7);
    int c0 = (t & 127) * 16;
    const float* src;
    if (r < L) {
      src = hs + (long)r * D;
    } else {
      int p = r - L;
      int id = ((p & 15) == 0) ? ids[p] : MASK_ID;
      src = emb + (long)id * D;
    }
    u16* dst = kv + (long)r * D + c0;
#pragma unroll
    for (int qy = 0; qy < 2; ++qy) {
      float4 a = *(const float4*)(src + c0 + qy * 8);
      float4 b = *(const float4*)(src + c0 + qy * 8 + 4);
      ushort4 o0, o1;
      o0.x = f2b(a.x); o0.y = f2b(a.y); o0.z = f2b(a.z); o0.w = f2b(a.w);
      o1.x = f2b(b.x); o1.y = f2b(b.y); o1.z = f2b(b.z); o1.w = f2b(b.w);
      *(ushort4*)(dst + qy * 8) = o0;
      *(ushort4*)(dst + qy * 8 + 4) = o1;
    }
  } else {
    int idx = bid - 512;
    int z = idx >> 8, tt = idx & 255;
    const float* W = (z == 0) ? Wq : (z == 1) ? Wk : (z == 2) ? Wv : Wo;
    u16* T = (z == 0) ? wtq : (z == 1) ? wtk : (z == 2) ? wtv : wto;
    transpose128(tile, W, T, D, D, (tt >> 4) * 128, (tt & 15) * 128);
  }
}

// ---------- 128x128 MFMA GEMM (2-phase, m97-structure), A [M][K], BT [N][K] ----------
// EPI_PLAIN: bf16 C store. EPI_CE: no C; per-row per-128-col-tile CE partials.
#define EPI_PLAIN 0
#define EPI_QKV 3
#define EPI_CE 4

template <int EPI>
__global__ __launch_bounds__(256) void gemm128(const u16* __restrict__ A, int lda,
                                               const u16* __restrict__ BT, int ldb,
                                               u16* __restrict__ C, int ldc,
                                               int Kd,
                                               const int* __restrict__ ids,
                                               float* __restrict__ PMAX, float* __restrict__ PSUM,
                                               int* __restrict__ PARGI, float* __restrict__ PTGT) {
  __shared__ __align__(16) char lds[16384];
  char* a_lds = lds;
  char* b_lds = lds + 8192;
  int tid = threadIdx.x;
  int lane = tid & 63;
  int wave = tid >> 6;
  int wr = wave >> 1, wc = wave & 1;
  int tm = blockIdx.x, tn = blockIdx.y;
  const u16* Ap = A + (long)tm * 128 * lda;
  const u16* Bp = BT + (long)tn * 128 * ldb;

  int soff = tid * 16;
  int srow = soff >> 6;
  int scol = (soff & 63) >> 1;
  char* aldsb = a_lds + wave * 1024;
  char* bldsb = b_lds + wave * 1024;

  f32x4 acc[4][4];
#pragma unroll
  for (int i = 0; i < 4; ++i)
#pragma unroll
    for (int j = 0; j < 4; ++j) acc[i][j] = (f32x4){0.f, 0.f, 0.f, 0.f};

  int lq = lane & 15, q = lane >> 4;
  for (int k0 = 0; k0 < Kd; k0 += 32) {
#pragma unroll
    for (int r = 0; r < 2; ++r) {
      gl_lds16(Ap + (long)(srow + r * 64) * lda + k0 + scol, aldsb + r * 4096);
      gl_lds16(Bp + (long)(srow + r * 64) * ldb + k0 + scol, bldsb + r * 4096);
    }
    __syncthreads();
    bf16x8 af[4], bfr[4];
    int ka = q << 4;
#pragma unroll
    for (int mi = 0; mi < 4; ++mi)
      af[mi] = *(const bf16x8*)(a_lds + (wr * 64 + mi * 16 + lq) * 64 + ka);
#pragma unroll
    for (int ni = 0; ni < 4; ++ni)
      bfr[ni] = *(const bf16x8*)(b_lds + (wc * 64 + ni * 16 + lq) * 64 + ka);
#pragma unroll
    for (int mi = 0; mi < 4; ++mi)
#pragma unroll
      for (int ni = 0; ni < 4; ++ni)
        acc[mi][ni] = __builtin_amdgcn_mfma_f32_16x16x32_bf16(af[mi], bfr[ni], acc[mi][ni], 0, 0, 0);
    __syncthreads();
  }

  if (EPI == EPI_CE) {
    // rows: wr*64 + mi*16 + q*4 + j ; cols: tn*128 + wc*64 + ni*16 + lq
    float* smax = (float*)lds;             // [128][2]
    float* ssum = smax + 256;
    int* sargi = (int*)(ssum + 256);
#pragma unroll
    for (int mi = 0; mi < 4; ++mi) {
#pragma unroll
      for (int j = 0; j < 4; ++j) {
        int lrow = wr * 64 + mi * 16 + q * 4 + j;
        long grow = (long)tm * 128 + lrow;
        int tgt = ids[grow];
        float v[4];
        float mx = -1e30f; int ai = 0;
#pragma unroll
        for (int ni = 0; ni < 4; ++ni) {
          v[ni] = acc[mi][ni][j];
          int col = tn * 128 + wc * 64 + ni * 16 + lq;
          if (col == tgt) PTGT[grow] = v[ni];
          if (v[ni] > mx) { mx = v[ni]; ai = col; }
        }
#pragma unroll
        for (int off = 1; off < 16; off <<= 1) {
          float om = __shfl_xor(mx, off);
          int oa = __shfl_xor(ai, off);
          if (om > mx || (om == mx && oa < ai)) { mx = om; ai = oa; }
        }
        float se = 0.f;
#pragma unroll
        for (int ni = 0; ni < 4; ++ni) se += __expf(v[ni] - mx);
#pragma unroll
        for (int off = 1; off < 16; off <<= 1) se += __shfl_xor(se, off);
        if (lq == 0) {
          smax[lrow * 2 + wc] = mx;
          ssum[lrow * 2 + wc] = se;
          sargi[lrow * 2 + wc] = ai;
        }
      }
    }
    __syncthreads();
    if (tid < 128) {
      int f = tid;
      float m0 = smax[f * 2], m1 = smax[f * 2 + 1];
      int a0 = sargi[f * 2], a1 = sargi[f * 2 + 1];
      float mt = m0; int at = a0;
      if (m1 > mt || (m1 == mt && a1 < at)) { mt = m1; at = a1; }
      float st = ssum[f * 2] * __expf(m0 - mt) + ssum[f * 2 + 1] * __expf(m1 - mt);
      long grow = (long)tm * 128 + f;
      PMAX[grow * 256 + tn] = mt;
      PSUM[grow * 256 + tn] = st;
      PARGI[grow * 256 + tn] = at;
    }
    return;
  }

  long crow0 = (long)tm * 128 + wr * 64 + (q << 2);
  int ccol0 = wc * 64 + lq;
#pragma unroll
  for (int mi = 0; mi < 4; ++mi) {
#pragma unroll
    for (int ni = 0; ni < 4; ++ni) {
      long col = (long)tn * 128 + ccol0 + ni * 16;
#pragma unroll
      for (int j = 0; j < 4; ++j) {
        long row = crow0 + mi * 16 + j;
        C[row * ldc + col] = f2b(acc[mi][ni][j]);
      }
    }
  }
}

// ---------- 256x256 8-phase MFMA GEMM body (round-6 form, QKV only) ----------
__device__ __forceinline__ void gemm256_qkv(char* lds, int tm, int tn,
                                            const u16* __restrict__ A, int lda,
                                            const u16* __restrict__ BT,
                                            int Kd,
                                            u16* __restrict__ Cq, u16* __restrict__ Ck,
                                            u16* __restrict__ Cv) {
  int tid = threadIdx.x, lane = tid & 63, w = tid >> 6;
  int wm = w >> 2, wn = w & 3;
  int lq = lane & 15, qq = lane >> 4;
  const char* Ap = (const char*)(A + (long)tm * 256 * lda);
  const char* Bp = (const char*)(BT + (long)tn * 256 * lda);
  int NT = Kd >> 6;
  int maxs = NT << 2;

  int swz = qq ^ ((lq >> 1) & 3);
  char* pA0 = lds + ((wm * 128 + lq) * 64 + (swz << 4));
  char* pA1 = pA0 + 65536;
  char* pB0 = lds + 32768 + ((wn * 64 + lq) * 64 + (swz << 4));
  char* pB1 = pB0 + 65536;
  int voff[2], lof[2];
#pragma unroll
  for (int l = 0; l < 2; ++l) {
    int o = tid * 16 + l * 8192;
    int rr = o >> 6;
    int ch = (o >> 4) & 3;
    int clog = ch ^ ((rr >> 1) & 3);
    voff[l] = (rr * lda + clog * 8) * 2;
    lof[l] = w * 1024 + l * 8192;
  }

  auto STAGE_SLOT = [&](int s) {
    if (s >= maxs) return;
    int tau = s >> 2, hh = s & 3;
    int kind = (hh & 1) ^ 1;
    int ks = hh >> 1;
    const char* src = kind ? Bp : Ap;
    long kb = (long)tau * 128 + ks * 64;
    char* dstb = lds + (tau & 1) * 65536 + kind * 32768 + ks * 16384;
#pragma unroll
    for (int l = 0; l < 2; ++l)
      gl_lds16(src + kb + voff[l], dstb + lof[l]);
  };

  f32x4 acc[8][4];
#pragma unroll
  for (int i = 0; i < 8; ++i)
#pragma unroll
    for (int j = 0; j < 4; ++j) acc[i][j] = (f32x4){0.f, 0.f, 0.f, 0.f};

  STAGE_SLOT(0); STAGE_SLOT(1); STAGE_SLOT(2); STAGE_SLOT(3);
  asm volatile("s_waitcnt vmcnt(4)" ::: "memory");
  STAGE_SLOT(4); STAGE_SLOT(5); STAGE_SLOT(6);
  asm volatile("s_waitcnt vmcnt(6)" ::: "memory");
  __builtin_amdgcn_s_barrier();
  __builtin_amdgcn_sched_barrier(0);

  bf16x8 bfr[4];

#define G256_PHASE(PA, PB, KS, MH, SLOT, WAITV)                                \
  {                                                                            \
    bf16x8 af[4];                                                              \
    if (MH == 0) {                                                             \
      bfr[0] = *(const bf16x8*)((PB) + (KS) * 16384 + 0 * 1024);               \
      bfr[1] = *(const bf16x8*)((PB) + (KS) * 16384 + 1 * 1024);               \
      bfr[2] = *(const bf16x8*)((PB) + (KS) * 16384 + 2 * 1024);               \
      bfr[3] = *(const bf16x8*)((PB) + (KS) * 16384 + 3 * 1024);               \
    }                                                                          \
    af[0] = *(const bf16x8*)((PA) + (KS) * 16384 + (MH * 4 + 0) * 1024);       \
    af[1] = *(const bf16x8*)((PA) + (KS) * 16384 + (MH * 4 + 1) * 1024);       \
    af[2] = *(const bf16x8*)((PA) + (KS) * 16384 + (MH * 4 + 2) * 1024);       \
    af[3] = *(const bf16x8*)((PA) + (KS) * 16384 + (MH * 4 + 3) * 1024);       \
    STAGE_SLOT(SLOT);                                                          \
    __builtin_amdgcn_sched_barrier(0);                                         \
    __builtin_amdgcn_s_barrier();                                              \
    asm volatile("s_waitcnt lgkmcnt(0)" ::: "memory");                         \
    __builtin_amdgcn_sched_barrier(0);                                         \
    __builtin_amdgcn_s_setprio(1);                                             \
    _Pragma("unroll")                                                          \
    for (int mi2 = 0; mi2 < 4; ++mi2)                                          \
      _Pragma("unroll")                                                        \
      for (int ni = 0; ni < 4; ++ni)                                           \
        acc[MH * 4 + mi2][ni] = __builtin_amdgcn_mfma_f32_16x16x32_bf16(       \
            af[mi2], bfr[ni], acc[MH * 4 + mi2][ni], 0, 0, 0);                 \
    __builtin_amdgcn_s_setprio(0);                                             \
    __builtin_amdgcn_sched_barrier(0);                                         \
    if (WAITV == 6) asm volatile("s_waitcnt vmcnt(6)" ::: "memory");           \
    else if (WAITV == 0) asm volatile("s_waitcnt vmcnt(0)" ::: "memory");      \
    __builtin_amdgcn_s_barrier();                                              \
    __builtin_amdgcn_sched_barrier(0);                                         \
  }

  for (int t = 0; t < NT; t += 2) {
    int s0 = 4 * t;
    int w4 = (t + 2 >= NT) ? 0 : 6;
    G256_PHASE(pA0, pB0, 0, 0, s0 + 7,  -1)
    G256_PHASE(pA0, pB0, 0, 1, s0 + 8,  -1)
    G256_PHASE(pA0, pB0, 1, 0, s0 + 9,  -1)
    G256_PHASE(pA0, pB0, 1, 1, s0 + 10, w4)
    G256_PHASE(pA1, pB1, 0, 0, s0 + 11, -1)
    G256_PHASE(pA1, pB1, 0, 1, s0 + 12, -1)
    G256_PHASE(pA1, pB1, 1, 0, s0 + 13, -1)
    G256_PHASE(pA1, pB1, 1, 1, s0 + 14, 6)
  }
#undef G256_PHASE

  long crow = (long)tm * 256 + wm * 128 + ((lane >> 4) << 2);
  long ccol = (long)tn * 256 + wn * 64 + lq;
#pragma unroll
  for (int mi = 0; mi < 8; ++mi)
#pragma unroll
    for (int ni = 0; ni < 4; ++ni)
#pragma unroll
      for (int j = 0; j < 4; ++j) {
        long row = crow + mi * 16 + j;
        long col = ccol + ni * 16;
        u16 val = f2b(acc[mi][ni][j]);
        if (col < 2048) {
          if (row >= 1024) Cq[(row - 1024) * D + col] = val;
        } else if (col < 4096) {
          Ck[row * D + (col - 2048)] = val;
        } else {
          Cv[(col - 4096) * KV + row] = val;
        }
      }
}

// ---------- mega2: QKV gemm256 (blocks 0..159) + lm-head transpose (blocks 160..511) ----------
__global__ __launch_bounds__(512, 2) void mega2(const u16* __restrict__ kv,
                                                const u16* __restrict__ wtq,
                                                u16* __restrict__ qb, u16* __restrict__ kb,
                                                u16* __restrict__ vt,
                                                const float* __restrict__ Wlm,
                                                u16* __restrict__ lmt) {
  __shared__ __align__(16) char lds[131072];
  int bid = blockIdx.x;
  if (bid < 160) {
    int wg = (bid & 7) * 20 + (bid >> 3);   // bijective XCD swizzle over 160
    int tm, tn;
    if (wg < 32) { tn = wg >> 2; tm = 4 + (wg & 3); }
    else { int e = wg - 32; tn = 8 + (e >> 3); tm = e & 7; }
    gemm256_qkv(lds, tm, tn, kv, D, wtq, D, qb, kb, vt);
  } else {
    for (int tile = bid - 160; tile < 4000; tile += 352) {
      int n0 = (tile % 250) * 128;
      int k0 = (tile / 250) * 128;
      transpose128((float*)lds, Wlm, lmt, D, VOCAB, k0, n0);
      __syncthreads();
    }
  }
}

// ---------- combine CE partials across 250 column tiles (stride 256) ----------
__global__ __launch_bounds__(256) void ce_combine(const float* __restrict__ PMAX,
                                                  const float* __restrict__ PSUM,
                                                  const int* __restrict__ PARGI,
                                                  const float* __restrict__ PTGT,
                                                  const int* __restrict__ ids,
                                                  float* __restrict__ rowbuf) {
  int row = blockIdx.x * 4 + (threadIdx.x >> 6);
  int lane = threadIdx.x & 63;
  const float* pm = PMAX + (long)row * 256;
  const float* ps = PSUM + (long)row * 256;
  const int* pi = PARGI + (long)row * 256;
  float lm[4]; int la[4]; float lsv[4];
  float mg = -1e30f; int ag = (1 << 30);
#pragma unroll
  for (int s = 0; s < 4; ++s) {
    int idx = lane + s * 64;
    bool ok = idx < 250;
    lm[s] = ok ? pm[idx] : -1e30f;
    la[s] = ok ? pi[idx] : (1 << 30);
    lsv[s] = ok ? ps[idx] : 0.f;
    if (lm[s] > mg || (lm[s] == mg && la[s] < ag)) { mg = lm[s]; ag = la[s]; }
  }
  for (int off = 1; off < 64; off <<= 1) {
    float om = __shfl_xor(mg, off);
    int oa = __shfl_xor(ag, off);
    if (om > mg || (om == mg && oa < ag)) { mg = om; ag = oa; }
  }
  float s = 0.f;
#pragma unroll
  for (int x = 0; x < 4; ++x) s += lsv[x] * __expf(lm[x] - mg);
  for (int off = 1; off < 64; off <<= 1) s += __shfl_xor(s, off);
  if (lane == 0) {
    rowbuf[row * 2] = mg + logf(s) - PTGT[row];
    rowbuf[row * 2 + 1] = (ag == ids[row]) ? 1.f : 0.f;
  }
}

// ---------- fused flash attention ----------
__global__ __launch_bounds__(256) void flash_attn(const u16* __restrict__ qb,
                                                  const u16* __restrict__ kb,
                                                  const u16* __restrict__ vt,
                                                  u16* __restrict__ ctx) {
  int tid = threadIdx.x;
  int lane = tid & 63;
  int wid = blockIdx.x * 4 + (tid >> 6);   // 0..1023
  int pairid = wid >> 1;
  int h = pairid >> 5;
  int pr = pairid & 31;
  int rb = (wid & 1) ? (63 - pr) : pr;     // balanced load
  int lq = lane & 15;
  int g = lane >> 4;
  const float scale = 0.08838834764831845f;  // 1/sqrt(128)

  const u16* qrow = qb + (long)(rb * 16 + lq) * D + h * HD + g * 8;
  bf16x8 qf[4];
#pragma unroll
  for (int c = 0; c < 4; ++c) qf[c] = *(const bf16x8*)(qrow + c * 32);

  f32x4 o[8];
#pragma unroll
  for (int i = 0; i < 8; ++i) o[i] = (f32x4){0.f, 0.f, 0.f, 0.f};
  float m = -1e30f, lsum = 0.f;

  int nb = rb + 1;
  for (int bp = 0; bp < nb; bp += 2) {
    bool validB = (bp + 1) < nb;
    int tokA = (bp < rb) ? bp * 16 : 1024 + rb * 16;
    int bB = bp + 1;
    int tokB = validB ? ((bB < rb) ? bB * 16 : 1024 + rb * 16) : tokA;

    f32x4 sA = (f32x4){0.f, 0.f, 0.f, 0.f};
    f32x4 sB = (f32x4){0.f, 0.f, 0.f, 0.f};
    const u16* ka = kb + (long)(tokA + lq) * D + h * HD + g * 8;
#pragma unroll
    for (int c = 0; c < 4; ++c) {
      bf16x8 kf = *(const bf16x8*)(ka + c * 32);
      sA = __builtin_amdgcn_mfma_f32_16x16x32_bf16(kf, qf[c], sA, 0, 0, 0);
    }
    if (validB) {
      const u16* kbp = kb + (long)(tokB + lq) * D + h * HD + g * 8;
#pragma unroll
      for (int c = 0; c < 4; ++c) {
        bf16x8 kf = *(const bf16x8*)(kbp + c * 32);
        sB = __builtin_amdgcn_mfma_f32_16x16x32_bf16(kf, qf[c], sB, 0, 0, 0);
      }
    }

    float s8[8];
#pragma unroll
    for (int j = 0; j < 4; ++j) s8[j] = sA[j] * scale;
#pragma unroll
    for (int j = 0; j < 4; ++j) s8[4 + j] = validB ? sB[j] * scale : -1e30f;
    float mx = s8[0];
#pragma unroll
    for (int j = 1; j < 8; ++j) mx = fmaxf(mx, s8[j]);
    mx = fmaxf(mx, __shfl_xor(mx, 16));
    mx = fmaxf(mx, __shfl_xor(mx, 32));
    float mn = fmaxf(m, mx);
    float sc_f = __expf(m - mn);
    m = mn;
    float p[8], ps = 0.f;
#pragma unroll
    for (int j = 0; j < 8; ++j) { p[j] = __expf(s8[j] - mn); ps += p[j]; }
    ps += __shfl_xor(ps, 16);
    ps += __shfl_xor(ps, 32);
    lsum = lsum * sc_f + ps;

    uint32 Aw0 = (uint32)f2b(p[0]) | ((uint32)f2b(p[1]) << 16);
    uint32 Aw1 = (uint32)f2b(p[2]) | ((uint32)f2b(p[3]) << 16);
    uint32 Bw0 = (uint32)f2b(p[4]) | ((uint32)f2b(p[5]) << 16);
    uint32 Bw1 = (uint32)f2b(p[6]) | ((uint32)f2b(p[7]) << 16);
    int s0 = (((2 * g) & 3) << 4) + lq;
    int s1 = (((2 * g + 1) & 3) << 4) + lq;
    uint32 a00 = (uint32)__shfl((int)Aw0, s0), a01 = (uint32)__shfl((int)Aw1, s0);
    uint32 a10 = (uint32)__shfl((int)Aw0, s1), a11 = (uint32)__shfl((int)Aw1, s1);
    uint32 b00 = (uint32)__shfl((int)Bw0, s0), b01 = (uint32)__shfl((int)Bw1, s0);
    uint32 b10 = (uint32)__shfl((int)Bw0, s1), b11 = (uint32)__shfl((int)Bw1, s1);
    union { uint32 u[4]; bf16x8 v; } pu;
    pu.u[0] = (g < 2) ? a00 : b00;
    pu.u[1] = (g < 2) ? a01 : b01;
    pu.u[2] = (g < 2) ? a10 : b10;
    pu.u[3] = (g < 2) ? a11 : b11;

#pragma unroll
    for (int nt = 0; nt < 8; ++nt)
#pragma unroll
      for (int j = 0; j < 4; ++j) o[nt][j] *= sc_f;
    int tok_g = (g < 2) ? (tokA + g * 8) : (tokB + (g - 2) * 8);
    const u16* vrow = vt + (long)(h * HD + lq) * KV + tok_g;
#pragma unroll
    for (int nt = 0; nt < 8; ++nt) {
      bf16x8 vf = *(const bf16x8*)(vrow + (long)nt * 16 * KV);
      o[nt] = __builtin_amdgcn_mfma_f32_16x16x32_bf16(vf, pu.v, o[nt], 0, 0, 0);
    }
  }

  float inv = 1.f / lsum;
  u16* cp = ctx + (long)(rb * 16 + lq) * D + h * HD + g * 4;
#pragma unroll
  for (int nt = 0; nt < 8; ++nt) {
    ushort4 st;
    st.x = f2b(o[nt][0] * inv); st.y = f2b(o[nt][1] * inv);
    st.z = f2b(o[nt][2] * inv); st.w = f2b(o[nt][3] * inv);
    *(ushort4*)(cp + nt * 16) = st;
  }
}

// ---------- final: masked mean loss + accuracy ----------
__global__ __launch_bounds__(256) void final_reduce(const float* __restrict__ rowbuf,
                                                    const float* __restrict__ loss_mask,
                                                    float* __restrict__ out) {
  int t = threadIdx.x;
  float ce = 0.f, cnt = 0.f, cor = 0.f;
  for (int r = t; r < L; r += 256) {
    bool valid = (r >= 16) && ((r & 15) != 0);
    float comb = loss_mask[r] * (valid ? 1.f : 0.f);
    if (comb > 1e-6f) {
      ce += rowbuf[r * 2];
      cor += rowbuf[r * 2 + 1];
      cnt += 1.f;
    }
  }
  for (int off = 1; off < 64; off <<= 1) {
    ce += __shfl_xor(ce, off);
    cnt += __shfl_xor(cnt, off);
    cor += __shfl_xor(cor, off);
  }
  __shared__ float s1[4], s2[4], s3[4];
  int lane = t & 63, w = t >> 6;
  if (lane == 0) { s1[w] = ce; s2[w] = cnt; s3[w] = cor; }
  __syncthreads();
  if (t == 0) {
    float C = s1[0] + s1[1] + s1[2] + s1[3];
    float N = s2[0] + s2[1] + s2[2] + s2[3];
    float R = s3[0] + s3[1] + s3[2] + s3[3];
    out[0] = C / N;
    out[1] = R / N;
  }
}

__global__ void ws_too_small(float* out, float mb) {
  if (threadIdx.x == 0) { out[0] = 1e6f + mb; out[1] = -1e6f; }
}

// ---------- launch ----------
extern "C" void kernel_launch(void* const* d_in, const int* in_sizes, int n_in,
                              void* d_out, int out_size, void* d_ws, size_t ws_size,
                              hipStream_t stream) {
  const int* ids = (const int*)d_in[0];
  const float* hs = (const float*)d_in[2];
  const float* lmask = (const float*)d_in[3];
  const float* emb = (const float*)d_in[4];
  const float* Wq = (const float*)d_in[5];
  const float* Wk = (const float*)d_in[6];
  const float* Wv = (const float*)d_in[7];
  const float* Wo = (const float*)d_in[8];
  const float* Wlm = (const float*)d_in[9];
  float* out = (float*)d_out;
  char* ws = (char*)d_ws;

  if (ws_size < (size_t)WS_NEED) {
    ws_too_small<<<1, 64, 0, stream>>>(out, (float)(ws_size >> 20));
    return;
  }

  u16* kv  = (u16*)(ws + OFF_KV);
  u16* wtq = (u16*)(ws + OFF_WTQ);
  u16* wtk = (u16*)(ws + OFF_WTK);
  u16* wtv = (u16*)(ws + OFF_WTV);
  u16* wto = (u16*)(ws + OFF_WTO);
  u16* qb  = (u16*)(ws + OFF_Q);
  u16* kb  = (u16*)(ws + OFF_K);
  u16* vt  = (u16*)(ws + OFF_VT);
  u16* ctx = (u16*)(ws + OFF_CTX);
  u16* hid = (u16*)(ws + OFF_HID);
  u16* lmt = (u16*)(ws + OFF_LMT);
  float* PMAX = (float*)(ws + OFF_PM);
  float* PSUM = (float*)(ws + OFF_PS);
  int* PARGI = (int*)(ws + OFF_PI);
  float* PTGT = (float*)(ws + OFF_PT);
  float* rowbuf = (float*)(ws + OFF_ROW);

  // prep kv + transpose Wq/Wk/Wv/Wo
  mega1<<<dim3(1536), 512, 0, stream>>>(hs, ids, emb, kv, Wq, Wk, Wv, Wo,
                                        wtq, wtk, wtv, wto);
  // QKV projection (8-phase 256^2, round-6 form) overlapped with lm-head transpose
  mega2<<<dim3(512), 512, 0, stream>>>(kv, wtq, qb, kb, vt, Wlm, lmt);

  // fused block-masked flash attention -> ctx
  flash_attn<<<dim3(256), 256, 0, stream>>>(qb, kb, vt, ctx);

  // hidden = ctx @ Wo (128^2 2-phase)
  gemm128<EPI_PLAIN><<<dim3(8, 16), 256, 0, stream>>>(ctx, D, wto, D, hid, D, D,
                                                      nullptr, nullptr, nullptr, nullptr, nullptr);

  // logits + fused CE partials: m97-structure 128^2, 2000 blocks (3+ blocks/CU)
  gemm128<EPI_CE><<<dim3(8, 250), 256, 0, stream>>>(hid, D, lmt, D, nullptr, 0, D,
                                                    ids, PMAX, PSUM, PARGI, PTGT);

  ce_combine<<<256, 256, 0, stream>>>(PMAX, PSUM, PARGI, PTGT, ids, rowbuf);
  final_reduce<<<1, 256, 0, stream>>>(rowbuf, lmask, out);
}

// Round 12
// 494.422 us; speedup vs baseline: 1.1050x; 1.0385x over previous
//
#include <hip/hip_runtime.h>

typedef unsigned int uint32;
typedef unsigned short u16;
typedef __attribute__((ext_vector_type(8))) short bf16x8;
typedef __attribute__((ext_vector_type(4))) float f32x4;

// ---------- helpers ----------
__device__ __forceinline__ u16 f2b(float f) {            // fp32 -> bf16 RNE
  uint32 u = __float_as_uint(f);
  u = (u + 0x7fffu + ((u >> 16) & 1u)) >> 16;
  return (u16)u;
}
__device__ __forceinline__ float b2f(u16 h) {
  return __uint_as_float(((uint32)h) << 16);
}
__device__ __forceinline__ void gl_lds16(const void* g, void* l) {
  typedef const __attribute__((address_space(1))) void* gp_t;
  typedef __attribute__((address_space(3))) void* lp_t;
  __builtin_amdgcn_global_load_lds((gp_t)g, (lp_t)l, 16, 0, 0);
}

// ---------- model constants ----------
#define L 1024
#define D 2048
#define NH 16
#define HD 128
#define VOCAB 32000
#define KV 2048
#define MASK_ID 31999

// ---------- ws layout (bytes) ----------
static constexpr long OFF_KV  = 0;                       // 2048*2048*2
static constexpr long OFF_WTQ = OFF_KV  + 8388608;
static constexpr long OFF_WTK = OFF_WTQ + 8388608;       // contiguous after WTQ (merged QKV GEMM)
static constexpr long OFF_WTV = OFF_WTK + 8388608;
static constexpr long OFF_WTO = OFF_WTV + 8388608;
static constexpr long OFF_Q   = OFF_WTO + 8388608;       // 1024*2048*2
static constexpr long OFF_K   = OFF_Q   + 4194304;       // 2048*2048*2
static constexpr long OFF_VT  = OFF_K   + 8388608;       // 2048*2048*2 (feature x token)
static constexpr long OFF_CTX = OFF_VT  + 8388608;       // 1024*2048*2
static constexpr long OFF_HID = OFF_CTX + 4194304;       // 1024*2048*2
static constexpr long OFF_LMT = OFF_HID + 4194304;       // 32000*2048*2
static constexpr long OFF_PM  = OFF_LMT + 131072000;     // 1024*128*4
static constexpr long OFF_PS  = OFF_PM  + 524288;
static constexpr long OFF_PI  = OFF_PS  + 524288;
static constexpr long OFF_PT  = OFF_PI  + 524288;        // 1024*4
static constexpr long OFF_ROW = OFF_PT  + 4096;          // 1024*2*4
static constexpr long WS_NEED = OFF_ROW + 8192;

// ---------- 128x128 transpose+convert tile body (512 threads, LDS passed in) ----------
__device__ __forceinline__ void transpose128(float* tile, const float* __restrict__ W,
                                             u16* __restrict__ WT,
                                             int Kd, int Nd, int k0, int n0) {
  int t = threadIdx.x;
  int r = t >> 2, cq = (t & 3) * 4;
#pragma unroll
  for (int p = 0; p < 8; ++p) {
    int c = cq + p * 16;
    float4 v = *(const float4*)(W + (long)(k0 + r) * Nd + n0 + c);
    float* d = tile + r * 129 + c;
    d[0] = v.x; d[1] = v.y; d[2] = v.z; d[3] = v.w;
  }
  __syncthreads();
  int q = t & 15, nn0 = t >> 4;   // nn0 0..31
#pragma unroll
  for (int p = 0; p < 4; ++p) {
    int nn = nn0 + p * 32;
    union { u16 v[8]; bf16x8 b; } u;
#pragma unroll
    for (int j = 0; j < 8; ++j) u.v[j] = f2b(tile[(q * 8 + j) * 129 + nn]);
    *(bf16x8*)(WT + (long)(n0 + nn) * Kd + k0 + q * 8) = u.b;
  }
}

// ---------- mega1: prep_kv + transpose of Wq/Wk/Wv/Wo (512 threads) ----------
__global__ __launch_bounds__(512) void mega1(const float* __restrict__ hs,
                                             const int* __restrict__ ids,
                                             const float* __restrict__ emb,
                                             u16* __restrict__ kv,
                                             const float* __restrict__ Wq, const float* __restrict__ Wk,
                                             const float* __restrict__ Wv, const float* __restrict__ Wo,
                                             u16* __restrict__ wtq, u16* __restrict__ wtk,
                                             u16* __restrict__ wtv, u16* __restrict__ wto) {
  __shared__ float tile[128 * 129];
  int bid = blockIdx.x;
  int t = threadIdx.x;
  if (bid < 512) {
    int r = bid * 4 + (t >> 7);
    int c0 = (t & 127) * 16;
    const float* src;
    if (r < L) {
      src = hs + (long)r * D;
    } else {
      int p = r - L;
      int id = ((p & 15) == 0) ? ids[p] : MASK_ID;
      src = emb + (long)id * D;
    }
    u16* dst = kv + (long)r * D + c0;
#pragma unroll
    for (int qy = 0; qy < 2; ++qy) {
      float4 a = *(const float4*)(src + c0 + qy * 8);
      float4 b = *(const float4*)(src + c0 + qy * 8 + 4);
      ushort4 o0, o1;
      o0.x = f2b(a.x); o0.y = f2b(a.y); o0.z = f2b(a.z); o0.w = f2b(a.w);
      o1.x = f2b(b.x); o1.y = f2b(b.y); o1.z = f2b(b.z); o1.w = f2b(b.w);
      *(ushort4*)(dst + qy * 8) = o0;
      *(ushort4*)(dst + qy * 8 + 4) = o1;
    }
  } else {
    int idx = bid - 512;
    int z = idx >> 8, tt = idx & 255;
    const float* W = (z == 0) ? Wq : (z == 1) ? Wk : (z == 2) ? Wv : Wo;
    u16* T = (z == 0) ? wtq : (z == 1) ? wtk : (z == 2) ? wtv : wto;
    transpose128(tile, W, T, D, D, (tt >> 4) * 128, (tt & 15) * 128);
  }
}

// ---------- 128x128 MFMA GEMM (2-phase), for hidden = ctx @ Wo ----------
__global__ __launch_bounds__(256) void gemm128p(const u16* __restrict__ A, int lda,
                                                const u16* __restrict__ BT, int ldb,
                                                u16* __restrict__ C, int ldc,
                                                int Kd) {
  __shared__ __align__(16) char lds[16384];
  char* a_lds = lds;
  char* b_lds = lds + 8192;
  int tid = threadIdx.x;
  int lane = tid & 63;
  int wave = tid >> 6;
  int wr = wave >> 1, wc = wave & 1;
  long tm = (long)blockIdx.x * 128;
  long tn = (long)blockIdx.y * 128;
  const u16* Ap = A + tm * lda;
  const u16* Bp = BT + tn * ldb;

  int soff = tid * 16;
  int srow = soff >> 6;
  int scol = (soff & 63) >> 1;
  char* aldsb = a_lds + wave * 1024;
  char* bldsb = b_lds + wave * 1024;

  f32x4 acc[4][4];
#pragma unroll
  for (int i = 0; i < 4; ++i)
#pragma unroll
    for (int j = 0; j < 4; ++j) acc[i][j] = (f32x4){0.f, 0.f, 0.f, 0.f};

  for (int k0 = 0; k0 < Kd; k0 += 32) {
#pragma unroll
    for (int r = 0; r < 2; ++r) {
      gl_lds16(Ap + (long)(srow + r * 64) * lda + k0 + scol, aldsb + r * 4096);
      gl_lds16(Bp + (long)(srow + r * 64) * ldb + k0 + scol, bldsb + r * 4096);
    }
    __syncthreads();
    bf16x8 af[4], bfr[4];
    int ka = (lane >> 4) << 4;
#pragma unroll
    for (int mi = 0; mi < 4; ++mi)
      af[mi] = *(const bf16x8*)(a_lds + (wr * 64 + mi * 16 + (lane & 15)) * 64 + ka);
#pragma unroll
    for (int ni = 0; ni < 4; ++ni)
      bfr[ni] = *(const bf16x8*)(b_lds + (wc * 64 + ni * 16 + (lane & 15)) * 64 + ka);
#pragma unroll
    for (int mi = 0; mi < 4; ++mi)
#pragma unroll
      for (int ni = 0; ni < 4; ++ni)
        acc[mi][ni] = __builtin_amdgcn_mfma_f32_16x16x32_bf16(af[mi], bfr[ni], acc[mi][ni], 0, 0, 0);
    __syncthreads();
  }

  long crow0 = tm + wr * 64 + ((lane >> 4) << 2);
  int ccol0 = wc * 64 + (lane & 15);
#pragma unroll
  for (int mi = 0; mi < 4; ++mi) {
#pragma unroll
    for (int ni = 0; ni < 4; ++ni) {
      long col = tn + ccol0 + ni * 16;
#pragma unroll
      for (int j = 0; j < 4; ++j) {
        long row = crow0 + mi * 16 + j;
        C[row * ldc + col] = f2b(acc[mi][ni][j]);
      }
    }
  }
}

// ---------- 256x256 8-phase MFMA GEMM (round-6 form) — QKV projection ----------
__device__ __forceinline__ void gemm256_qkv(char* lds, int tm, int tn,
                                            const u16* __restrict__ A, int lda,
                                            const u16* __restrict__ BT,
                                            int Kd,
                                            u16* __restrict__ Cq, u16* __restrict__ Ck,
                                            u16* __restrict__ Cv) {
  int tid = threadIdx.x, lane = tid & 63, w = tid >> 6;
  int wm = w >> 2, wn = w & 3;
  int lq = lane & 15, qq = lane >> 4;
  const char* Ap = (const char*)(A + (long)tm * 256 * lda);
  const char* Bp = (const char*)(BT + (long)tn * 256 * lda);
  int NT = Kd >> 6;
  int maxs = NT << 2;

  int swz = qq ^ ((lq >> 1) & 3);
  char* pA0 = lds + ((wm * 128 + lq) * 64 + (swz << 4));
  char* pA1 = pA0 + 65536;
  char* pB0 = lds + 32768 + ((wn * 64 + lq) * 64 + (swz << 4));
  char* pB1 = pB0 + 65536;
  int voff[2], lof[2];
#pragma unroll
  for (int l = 0; l < 2; ++l) {
    int o = tid * 16 + l * 8192;
    int rr = o >> 6;
    int ch = (o >> 4) & 3;
    int clog = ch ^ ((rr >> 1) & 3);
    voff[l] = (rr * lda + clog * 8) * 2;
    lof[l] = w * 1024 + l * 8192;
  }

  auto STAGE_SLOT = [&](int s) {
    if (s >= maxs) return;
    int tau = s >> 2, hh = s & 3;
    int kind = (hh & 1) ^ 1;
    int ks = hh >> 1;
    const char* src = kind ? Bp : Ap;
    long kb = (long)tau * 128 + ks * 64;
    char* dstb = lds + (tau & 1) * 65536 + kind * 32768 + ks * 16384;
#pragma unroll
    for (int l = 0; l < 2; ++l)
      gl_lds16(src + kb + voff[l], dstb + lof[l]);
  };

  f32x4 acc[8][4];
#pragma unroll
  for (int i = 0; i < 8; ++i)
#pragma unroll
    for (int j = 0; j < 4; ++j) acc[i][j] = (f32x4){0.f, 0.f, 0.f, 0.f};

  STAGE_SLOT(0); STAGE_SLOT(1); STAGE_SLOT(2); STAGE_SLOT(3);
  asm volatile("s_waitcnt vmcnt(4)" ::: "memory");
  STAGE_SLOT(4); STAGE_SLOT(5); STAGE_SLOT(6);
  asm volatile("s_waitcnt vmcnt(6)" ::: "memory");
  __builtin_amdgcn_s_barrier();
  __builtin_amdgcn_sched_barrier(0);

  bf16x8 bfr[4];

#define G256_PHASE(PA, PB, KS, MH, SLOT, WAITV)                                \
  {                                                                            \
    bf16x8 af[4];                                                              \
    if (MH == 0) {                                                             \
      bfr[0] = *(const bf16x8*)((PB) + (KS) * 16384 + 0 * 1024);               \
      bfr[1] = *(const bf16x8*)((PB) + (KS) * 16384 + 1 * 1024);               \
      bfr[2] = *(const bf16x8*)((PB) + (KS) * 16384 + 2 * 1024);               \
      bfr[3] = *(const bf16x8*)((PB) + (KS) * 16384 + 3 * 1024);               \
    }                                                                          \
    af[0] = *(const bf16x8*)((PA) + (KS) * 16384 + (MH * 4 + 0) * 1024);       \
    af[1] = *(const bf16x8*)((PA) + (KS) * 16384 + (MH * 4 + 1) * 1024);       \
    af[2] = *(const bf16x8*)((PA) + (KS) * 16384 + (MH * 4 + 2) * 1024);       \
    af[3] = *(const bf16x8*)((PA) + (KS) * 16384 + (MH * 4 + 3) * 1024);       \
    STAGE_SLOT(SLOT);                                                          \
    __builtin_amdgcn_sched_barrier(0);                                         \
    __builtin_amdgcn_s_barrier();                                              \
    asm volatile("s_waitcnt lgkmcnt(0)" ::: "memory");                         \
    __builtin_amdgcn_sched_barrier(0);                                         \
    __builtin_amdgcn_s_setprio(1);                                             \
    _Pragma("unroll")                                                          \
    for (int mi2 = 0; mi2 < 4; ++mi2)                                          \
      _Pragma("unroll")                                                        \
      for (int ni = 0; ni < 4; ++ni)                                           \
        acc[MH * 4 + mi2][ni] = __builtin_amdgcn_mfma_f32_16x16x32_bf16(       \
            af[mi2], bfr[ni], acc[MH * 4 + mi2][ni], 0, 0, 0);                 \
    __builtin_amdgcn_s_setprio(0);                                             \
    __builtin_amdgcn_sched_barrier(0);                                         \
    if (WAITV == 6) asm volatile("s_waitcnt vmcnt(6)" ::: "memory");           \
    else if (WAITV == 0) asm volatile("s_waitcnt vmcnt(0)" ::: "memory");      \
    __builtin_amdgcn_s_barrier();                                              \
    __builtin_amdgcn_sched_barrier(0);                                         \
  }

  for (int t = 0; t < NT; t += 2) {
    int s0 = 4 * t;
    int w4 = (t + 2 >= NT) ? 0 : 6;
    G256_PHASE(pA0, pB0, 0, 0, s0 + 7,  -1)
    G256_PHASE(pA0, pB0, 0, 1, s0 + 8,  -1)
    G256_PHASE(pA0, pB0, 1, 0, s0 + 9,  -1)
    G256_PHASE(pA0, pB0, 1, 1, s0 + 10, w4)
    G256_PHASE(pA1, pB1, 0, 0, s0 + 11, -1)
    G256_PHASE(pA1, pB1, 0, 1, s0 + 12, -1)
    G256_PHASE(pA1, pB1, 1, 0, s0 + 13, -1)
    G256_PHASE(pA1, pB1, 1, 1, s0 + 14, 6)
  }
#undef G256_PHASE

  long crow = (long)tm * 256 + wm * 128 + ((lane >> 4) << 2);
  long ccol = (long)tn * 256 + wn * 64 + lq;
#pragma unroll
  for (int mi = 0; mi < 8; ++mi)
#pragma unroll
    for (int ni = 0; ni < 4; ++ni)
#pragma unroll
      for (int j = 0; j < 4; ++j) {
        long row = crow + mi * 16 + j;
        long col = ccol + ni * 16;
        u16 val = f2b(acc[mi][ni][j]);
        if (col < 2048) {
          if (row >= 1024) Cq[(row - 1024) * D + col] = val;
        } else if (col < 4096) {
          Ck[row * D + (col - 2048)] = val;
        } else {
          Cv[(col - 4096) * KV + row] = val;
        }
      }
}

// ---------- mega2: QKV gemm256 (blocks 0..159) + lm-head transpose (blocks 160..511) ----------
__global__ __launch_bounds__(512, 2) void mega2(const u16* __restrict__ kv,
                                                const u16* __restrict__ wtq,
                                                u16* __restrict__ qb, u16* __restrict__ kb,
                                                u16* __restrict__ vt,
                                                const float* __restrict__ Wlm,
                                                u16* __restrict__ lmt) {
  __shared__ __align__(16) char lds[131072];
  int bid = blockIdx.x;
  if (bid < 160) {
    int wg = (bid & 7) * 20 + (bid >> 3);   // bijective XCD swizzle over 160
    int tm, tn;
    if (wg < 32) { tn = wg >> 2; tm = 4 + (wg & 3); }
    else { int e = wg - 32; tn = 8 + (e >> 3); tm = e & 7; }
    gemm256_qkv(lds, tm, tn, kv, D, wtq, D, qb, kb, vt);
  } else {
    for (int tile = bid - 160; tile < 4000; tile += 352) {
      int n0 = (tile % 250) * 128;
      int k0 = (tile / 250) * 128;
      transpose128((float*)lds, Wlm, lmt, D, VOCAB, k0, n0);
      __syncthreads();
    }
  }
}

// ---------- lm logits + fused CE: merged 2-KS phases with counted lgkmcnt ----------
// Per K-32 phase: bf+af0 reads, [pin], af1 reads, 2 stage slots, barrier,
// lgkmcnt(4) -> MFMA MH0 (af1 reads complete under it), lgkmcnt(0) -> MFMA MH1.
// vmcnt tails 8/8/8/6 (last pair 8/4/0/0) — WAR/RAW audited.
__global__ __launch_bounds__(512, 2) void gemm256_ce(const u16* __restrict__ A,
                                                     const u16* __restrict__ BT,
                                                     const int* __restrict__ ids,
                                                     float* __restrict__ PMAX, float* __restrict__ PSUM,
                                                     int* __restrict__ PARGI, float* __restrict__ PTGT) {
  __shared__ __align__(16) char lds[131072];
  int nwg = gridDim.x;
  int orig = blockIdx.x;
  int q8 = nwg >> 3, r8 = nwg & 7;
  int xcd = orig & 7, idx = orig >> 3;
  int wg = (xcd < r8 ? xcd * (q8 + 1) : r8 * (q8 + 1) + (xcd - r8) * q8) + idx;
  int tm = wg % 4, tn = wg / 4;

  int tid = threadIdx.x, lane = tid & 63, w = tid >> 6;
  int wm = w >> 2, wn = w & 3;
  int lq = lane & 15, qq = lane >> 4;
  const char* Ap = (const char*)(A + (long)tm * 256 * D);
  const char* Bp = (const char*)(BT + (long)tn * 256 * D);
  const int NT = D >> 6;          // 32
  const int maxs = NT << 2;       // 128

  int swz = qq ^ ((lq >> 1) & 3);
  char* pA0 = lds + ((wm * 128 + lq) * 64 + (swz << 4));
  char* pA1 = pA0 + 65536;
  char* pB0 = lds + 32768 + ((wn * 64 + lq) * 64 + (swz << 4));
  char* pB1 = pB0 + 65536;
  int voff[2], lof[2];
#pragma unroll
  for (int l = 0; l < 2; ++l) {
    int o = tid * 16 + l * 8192;
    int rr = o >> 6;
    int ch = (o >> 4) & 3;
    int clog = ch ^ ((rr >> 1) & 3);
    voff[l] = (rr * D + clog * 8) * 2;
    lof[l] = w * 1024 + l * 8192;
  }

  auto STAGE_SLOT = [&](int s) {
    if (s >= maxs) return;
    int tau = s >> 2, hh = s & 3;
    int kind = (hh & 1) ^ 1;
    int ks = hh >> 1;
    const char* src = kind ? Bp : Ap;
    long kb = (long)tau * 128 + ks * 64;
    char* dstb = lds + (tau & 1) * 65536 + kind * 32768 + ks * 16384;
#pragma unroll
    for (int l = 0; l < 2; ++l)
      gl_lds16(src + kb + voff[l], dstb + lof[l]);
  };

  f32x4 acc[8][4];
#pragma unroll
  for (int i = 0; i < 8; ++i)
#pragma unroll
    for (int j = 0; j < 4; ++j) acc[i][j] = (f32x4){0.f, 0.f, 0.f, 0.f};

  // prologue: slots 0..5; land 0,1,2 (3 slots = 6 loads in flight)
  STAGE_SLOT(0); STAGE_SLOT(1); STAGE_SLOT(2);
  STAGE_SLOT(3); STAGE_SLOT(4); STAGE_SLOT(5);
  asm volatile("s_waitcnt vmcnt(6)" ::: "memory");
  __builtin_amdgcn_s_barrier();
  __builtin_amdgcn_sched_barrier(0);

  bf16x8 bf[4], af0[4], af1[4];

#define MPHASE(PA, PB, KS, SL1, SL2, TAILV)                                    \
  {                                                                            \
    bf[0] = *(const bf16x8*)((PB) + (KS) * 16384 + 0 * 1024);                  \
    bf[1] = *(const bf16x8*)((PB) + (KS) * 16384 + 1 * 1024);                  \
    bf[2] = *(const bf16x8*)((PB) + (KS) * 16384 + 2 * 1024);                  \
    bf[3] = *(const bf16x8*)((PB) + (KS) * 16384 + 3 * 1024);                  \
    af0[0] = *(const bf16x8*)((PA) + (KS) * 16384 + 0 * 1024);                 \
    af0[1] = *(const bf16x8*)((PA) + (KS) * 16384 + 1 * 1024);                 \
    af0[2] = *(const bf16x8*)((PA) + (KS) * 16384 + 2 * 1024);                 \
    af0[3] = *(const bf16x8*)((PA) + (KS) * 16384 + 3 * 1024);                 \
    __builtin_amdgcn_sched_barrier(0);  /* pin bf+af0 first */                 \
    af1[0] = *(const bf16x8*)((PA) + (KS) * 16384 + 4 * 1024);                 \
    af1[1] = *(const bf16x8*)((PA) + (KS) * 16384 + 5 * 1024);                 \
    af1[2] = *(const bf16x8*)((PA) + (KS) * 16384 + 6 * 1024);                 \
    af1[3] = *(const bf16x8*)((PA) + (KS) * 16384 + 7 * 1024);                 \
    STAGE_SLOT(SL1); STAGE_SLOT(SL2);                                          \
    __builtin_amdgcn_sched_barrier(0);                                         \
    __builtin_amdgcn_s_barrier();                                              \
    asm volatile("s_waitcnt lgkmcnt(4)" ::: "memory");                         \
    __builtin_amdgcn_sched_barrier(0);                                         \
    __builtin_amdgcn_s_setprio(1);                                             \
    _Pragma("unroll")                                                          \
    for (int mi2 = 0; mi2 < 4; ++mi2)                                          \
      _Pragma("unroll")                                                        \
      for (int ni2 = 0; ni2 < 4; ++ni2)                                        \
        acc[mi2][ni2] = __builtin_amdgcn_mfma_f32_16x16x32_bf16(               \
            af0[mi2], bf[ni2], acc[mi2][ni2], 0, 0, 0);                        \
    __builtin_amdgcn_s_setprio(0);                                             \
    __builtin_amdgcn_sched_barrier(0);                                         \
    asm volatile("s_waitcnt lgkmcnt(0)" ::: "memory");                         \
    __builtin_amdgcn_sched_barrier(0);                                         \
    __builtin_amdgcn_s_setprio(1);                                             \
    _Pragma("unroll")                                                          \
    for (int mi2 = 0; mi2 < 4; ++mi2)                                          \
      _Pragma("unroll")                                                        \
      for (int ni2 = 0; ni2 < 4; ++ni2)                                        \
        acc[4 + mi2][ni2] = __builtin_amdgcn_mfma_f32_16x16x32_bf16(           \
            af1[mi2], bf[ni2], acc[4 + mi2][ni2], 0, 0, 0);                    \
    __builtin_amdgcn_s_setprio(0);                                             \
    __builtin_amdgcn_sched_barrier(0);                                         \
    {                                                                          \
      int tv_ = (TAILV);                                                       \
      if (tv_ == 8) asm volatile("s_waitcnt vmcnt(8)" ::: "memory");           \
      else if (tv_ == 6) asm volatile("s_waitcnt vmcnt(6)" ::: "memory");      \
      else if (tv_ == 4) asm volatile("s_waitcnt vmcnt(4)" ::: "memory");      \
      else if (tv_ == 0) asm volatile("s_waitcnt vmcnt(0)" ::: "memory");      \
    }                                                                          \
    __builtin_amdgcn_s_barrier();                                              \
    __builtin_amdgcn_sched_barrier(0);                                         \
  }

  for (int t = 0; t < NT; t += 2) {
    int s0 = 4 * t;
    bool lastp = (t + 2 >= NT);
    MPHASE(pA0, pB0, 0, s0 + 6,  s0 + 7,  8)
    MPHASE(pA0, pB0, 1, s0 + 8,  s0 + 9,  lastp ? 4 : 8)
    MPHASE(pA1, pB1, 0, s0 + 10, s0 + 11, lastp ? 0 : 8)
    MPHASE(pA1, pB1, 1, s0 + 12, s0 + 13, lastp ? 0 : 6)
  }
#undef MPHASE

  // CE epilogue (per-row partials over this 256-col tile)
  __syncthreads();
  float* smax = (float*)lds;            // [256][4]
  float* ssum = smax + 1024;
  int* sargi = (int*)(ssum + 1024);
#pragma unroll
  for (int mi = 0; mi < 8; ++mi) {
#pragma unroll
    for (int j = 0; j < 4; ++j) {
      int lrow = mi * 16 + qq * 4 + j;
      long grow = (long)tm * 256 + wm * 128 + lrow;
      int tgt = ids[grow];
      float v[4];
      float mx = -1e30f; int ai = 0;
#pragma unroll
      for (int ni = 0; ni < 4; ++ni) {
        v[ni] = acc[mi][ni][j];
        int col = tn * 256 + wn * 64 + ni * 16 + lq;
        if (col == tgt) PTGT[grow] = v[ni];
        if (v[ni] > mx) { mx = v[ni]; ai = col; }
      }
#pragma unroll
      for (int off = 1; off < 16; off <<= 1) {
        float om = __shfl_xor(mx, off);
        int oa = __shfl_xor(ai, off);
        if (om > mx || (om == mx && oa < ai)) { mx = om; ai = oa; }
      }
      float se = 0.f;
#pragma unroll
      for (int ni = 0; ni < 4; ++ni) se += __expf(v[ni] - mx);
#pragma unroll
      for (int off = 1; off < 16; off <<= 1) se += __shfl_xor(se, off);
      if (lq == 0) {
        int f = wm * 128 + lrow;
        smax[f * 4 + wn] = mx;
        ssum[f * 4 + wn] = se;
        sargi[f * 4 + wn] = ai;
      }
    }
  }
  __syncthreads();
  if (lane < 32) {
    int f = w * 32 + lane;
    float m_t = smax[f * 4]; int a_t = sargi[f * 4];
#pragma unroll
    for (int x = 1; x < 4; ++x) {
      float om = smax[f * 4 + x]; int oa = sargi[f * 4 + x];
      if (om > m_t || (om == m_t && oa < a_t)) { m_t = om; a_t = oa; }
    }
    float s_t = 0.f;
#pragma unroll
    for (int x = 0; x < 4; ++x) s_t += ssum[f * 4 + x] * __expf(smax[f * 4 + x] - m_t);
    long grow = (long)tm * 256 + f;
    PMAX[grow * 128 + tn] = m_t;
    PSUM[grow * 128 + tn] = s_t;
    PARGI[grow * 128 + tn] = a_t;
  }
}

// ---------- combine CE partials across 125 column tiles ----------
__global__ __launch_bounds__(256) void ce_combine(const float* __restrict__ PMAX,
                                                  const float* __restrict__ PSUM,
                                                  const int* __restrict__ PARGI,
                                                  const float* __restrict__ PTGT,
                                                  const int* __restrict__ ids,
                                                  float* __restrict__ rowbuf) {
  int row = blockIdx.x * 4 + (threadIdx.x >> 6);
  int lane = threadIdx.x & 63;
  const float* pm = PMAX + (long)row * 128;
  const float* ps = PSUM + (long)row * 128;
  const int* pi = PARGI + (long)row * 128;
  float m0 = (lane < 125) ? pm[lane] : -1e30f;
  int a0 = (lane < 125) ? pi[lane] : (1 << 30);
  float m1 = (lane + 64 < 125) ? pm[lane + 64] : -1e30f;
  int a1 = (lane + 64 < 125) ? pi[lane + 64] : (1 << 30);
  float mg = m0; int ag = a0;
  if (m1 > mg || (m1 == mg && a1 < ag)) { mg = m1; ag = a1; }
  for (int off = 1; off < 64; off <<= 1) {
    float om = __shfl_xor(mg, off);
    int oa = __shfl_xor(ag, off);
    if (om > mg || (om == mg && oa < ag)) { mg = om; ag = oa; }
  }
  float s = 0.f;
  if (lane < 125) s += ps[lane] * __expf(m0 - mg);
  if (lane + 64 < 125) s += ps[lane + 64] * __expf(m1 - mg);
  for (int off = 1; off < 64; off <<= 1) s += __shfl_xor(s, off);
  if (lane == 0) {
    rowbuf[row * 2] = mg + logf(s) - PTGT[row];
    rowbuf[row * 2 + 1] = (ag == ids[row]) ? 1.f : 0.f;
  }
}

// ---------- fused flash attention ----------
__global__ __launch_bounds__(256) void flash_attn(const u16* __restrict__ qb,
                                                  const u16* __restrict__ kb,
                                                  const u16* __restrict__ vt,
                                                  u16* __restrict__ ctx) {
  int tid = threadIdx.x;
  int lane = tid & 63;
  int wid = blockIdx.x * 4 + (tid >> 6);   // 0..1023
  int pairid = wid >> 1;
  int h = pairid >> 5;
  int pr = pairid & 31;
  int rb = (wid & 1) ? (63 - pr) : pr;     // balanced load
  int lq = lane & 15;
  int g = lane >> 4;
  const float scale = 0.08838834764831845f;  // 1/sqrt(128)

  const u16* qrow = qb + (long)(rb * 16 + lq) * D + h * HD + g * 8;
  bf16x8 qf[4];
#pragma unroll
  for (int c = 0; c < 4; ++c) qf[c] = *(const bf16x8*)(qrow + c * 32);

  f32x4 o[8];
#pragma unroll
  for (int i = 0; i < 8; ++i) o[i] = (f32x4){0.f, 0.f, 0.f, 0.f};
  float m = -1e30f, lsum = 0.f;

  int nb = rb + 1;
  for (int bp = 0; bp < nb; bp += 2) {
    bool validB = (bp + 1) < nb;
    int tokA = (bp < rb) ? bp * 16 : 1024 + rb * 16;
    int bB = bp + 1;
    int tokB = validB ? ((bB < rb) ? bB * 16 : 1024 + rb * 16) : tokA;

    f32x4 sA = (f32x4){0.f, 0.f, 0.f, 0.f};
    f32x4 sB = (f32x4){0.f, 0.f, 0.f, 0.f};
    const u16* ka = kb + (long)(tokA + lq) * D + h * HD + g * 8;
#pragma unroll
    for (int c = 0; c < 4; ++c) {
      bf16x8 kf = *(const bf16x8*)(ka + c * 32);
      sA = __builtin_amdgcn_mfma_f32_16x16x32_bf16(kf, qf[c], sA, 0, 0, 0);
    }
    if (validB) {
      const u16* kbp = kb + (long)(tokB + lq) * D + h * HD + g * 8;
#pragma unroll
      for (int c = 0; c < 4; ++c) {
        bf16x8 kf = *(const bf16x8*)(kbp + c * 32);
        sB = __builtin_amdgcn_mfma_f32_16x16x32_bf16(kf, qf[c], sB, 0, 0, 0);
      }
    }

    float s8[8];
#pragma unroll
    for (int j = 0; j < 4; ++j) s8[j] = sA[j] * scale;
#pragma unroll
    for (int j = 0; j < 4; ++j) s8[4 + j] = validB ? sB[j] * scale : -1e30f;
    float mx = s8[0];
#pragma unroll
    for (int j = 1; j < 8; ++j) mx = fmaxf(mx, s8[j]);
    mx = fmaxf(mx, __shfl_xor(mx, 16));
    mx = fmaxf(mx, __shfl_xor(mx, 32));
    float mn = fmaxf(m, mx);
    float sc_f = __expf(m - mn);
    m = mn;
    float p[8], ps = 0.f;
#pragma unroll
    for (int j = 0; j < 8; ++j) { p[j] = __expf(s8[j] - mn); ps += p[j]; }
    ps += __shfl_xor(ps, 16);
    ps += __shfl_xor(ps, 32);
    lsum = lsum * sc_f + ps;

    uint32 Aw0 = (uint32)f2b(p[0]) | ((uint32)f2b(p[1]) << 16);
    uint32 Aw1 = (uint32)f2b(p[2]) | ((uint32)f2b(p[3]) << 16);
    uint32 Bw0 = (uint32)f2b(p[4]) | ((uint32)f2b(p[5]) << 16);
    uint32 Bw1 = (uint32)f2b(p[6]) | ((uint32)f2b(p[7]) << 16);
    int s0 = (((2 * g) & 3) << 4) + lq;
    int s1 = (((2 * g + 1) & 3) << 4) + lq;
    uint32 a00 = (uint32)__shfl((int)Aw0, s0), a01 = (uint32)__shfl((int)Aw1, s0);
    uint32 a10 = (uint32)__shfl((int)Aw0, s1), a11 = (uint32)__shfl((int)Aw1, s1);
    uint32 b00 = (uint32)__shfl((int)Bw0, s0), b01 = (uint32)__shfl((int)Bw1, s0);
    uint32 b10 = (uint32)__shfl((int)Bw0, s1), b11 = (uint32)__shfl((int)Bw1, s1);
    union { uint32 u[4]; bf16x8 v; } pu;
    pu.u[0] = (g < 2) ? a00 : b00;
    pu.u[1] = (g < 2) ? a01 : b01;
    pu.u[2] = (g < 2) ? a10 : b10;
    pu.u[3] = (g < 2) ? a11 : b11;

#pragma unroll
    for (int nt = 0; nt < 8; ++nt)
#pragma unroll
      for (int j = 0; j < 4; ++j) o[nt][j] *= sc_f;
    int tok_g = (g < 2) ? (tokA + g * 8) : (tokB + (g - 2) * 8);
    const u16* vrow = vt + (long)(h * HD + lq) * KV + tok_g;
#pragma unroll
    for (int nt = 0; nt < 8; ++nt) {
      bf16x8 vf = *(const bf16x8*)(vrow + (long)nt * 16 * KV);
      o[nt] = __builtin_amdgcn_mfma_f32_16x16x32_bf16(vf, pu.v, o[nt], 0, 0, 0);
    }
  }

  float inv = 1.f / lsum;
  u16* cp = ctx + (long)(rb * 16 + lq) * D + h * HD + g * 4;
#pragma unroll
  for (int nt = 0; nt < 8; ++nt) {
    ushort4 st;
    st.x = f2b(o[nt][0] * inv); st.y = f2b(o[nt][1] * inv);
    st.z = f2b(o[nt][2] * inv); st.w = f2b(o[nt][3] * inv);
    *(ushort4*)(cp + nt * 16) = st;
  }
}

// ---------- final: masked mean loss + accuracy ----------
__global__ __launch_bounds__(256) void final_reduce(const float* __restrict__ rowbuf,
                                                    const float* __restrict__ loss_mask,
                                                    float* __restrict__ out) {
  int t = threadIdx.x;
  float ce = 0.f, cnt = 0.f, cor = 0.f;
  for (int r = t; r < L; r += 256) {
    bool valid = (r >= 16) && ((r & 15) != 0);
    float comb = loss_mask[r] * (valid ? 1.f : 0.f);
    if (comb > 1e-6f) {
      ce += rowbuf[r * 2];
      cor += rowbuf[r * 2 + 1];
      cnt += 1.f;
    }
  }
  for (int off = 1; off < 64; off <<= 1) {
    ce += __shfl_xor(ce, off);
    cnt += __shfl_xor(cnt, off);
    cor += __shfl_xor(cor, off);
  }
  __shared__ float s1[4], s2[4], s3[4];
  int lane = t & 63, w = t >> 6;
  if (lane == 0) { s1[w] = ce; s2[w] = cnt; s3[w] = cor; }
  __syncthreads();
  if (t == 0) {
    float C = s1[0] + s1[1] + s1[2] + s1[3];
    float N = s2[0] + s2[1] + s2[2] + s2[3];
    float R = s3[0] + s3[1] + s3[2] + s3[3];
    out[0] = C / N;
    out[1] = R / N;
  }
}

__global__ void ws_too_small(float* out, float mb) {
  if (threadIdx.x == 0) { out[0] = 1e6f + mb; out[1] = -1e6f; }
}

// ---------- launch ----------
extern "C" void kernel_launch(void* const* d_in, const int* in_sizes, int n_in,
                              void* d_out, int out_size, void* d_ws, size_t ws_size,
                              hipStream_t stream) {
  const int* ids = (const int*)d_in[0];
  const float* hs = (const float*)d_in[2];
  const float* lmask = (const float*)d_in[3];
  const float* emb = (const float*)d_in[4];
  const float* Wq = (const float*)d_in[5];
  const float* Wk = (const float*)d_in[6];
  const float* Wv = (const float*)d_in[7];
  const float* Wo = (const float*)d_in[8];
  const float* Wlm = (const float*)d_in[9];
  float* out = (float*)d_out;
  char* ws = (char*)d_ws;

  if (ws_size < (size_t)WS_NEED) {
    ws_too_small<<<1, 64, 0, stream>>>(out, (float)(ws_size >> 20));
    return;
  }

  u16* kv  = (u16*)(ws + OFF_KV);
  u16* wtq = (u16*)(ws + OFF_WTQ);
  u16* wtk = (u16*)(ws + OFF_WTK);
  u16* wtv = (u16*)(ws + OFF_WTV);
  u16* wto = (u16*)(ws + OFF_WTO);
  u16* qb  = (u16*)(ws + OFF_Q);
  u16* kb  = (u16*)(ws + OFF_K);
  u16* vt  = (u16*)(ws + OFF_VT);
  u16* ctx = (u16*)(ws + OFF_CTX);
  u16* hid = (u16*)(ws + OFF_HID);
  u16* lmt = (u16*)(ws + OFF_LMT);
  float* PMAX = (float*)(ws + OFF_PM);
  float* PSUM = (float*)(ws + OFF_PS);
  int* PARGI = (int*)(ws + OFF_PI);
  float* PTGT = (float*)(ws + OFF_PT);
  float* rowbuf = (float*)(ws + OFF_ROW);

  // prep kv + transpose Wq/Wk/Wv/Wo
  mega1<<<dim3(1536), 512, 0, stream>>>(hs, ids, emb, kv, Wq, Wk, Wv, Wo,
                                        wtq, wtk, wtv, wto);
  // QKV projection (8-phase 256^2, round-6 form) overlapped with lm-head transpose
  mega2<<<dim3(512), 512, 0, stream>>>(kv, wtq, qb, kb, vt, Wlm, lmt);

  // fused block-masked flash attention -> ctx
  flash_attn<<<dim3(256), 256, 0, stream>>>(qb, kb, vt, ctx);

  // hidden = ctx @ Wo (128^2 2-phase)
  gemm128p<<<dim3(8, 16), 256, 0, stream>>>(ctx, D, wto, D, hid, D, D);

  // logits + fused CE partials (merged counted-lgkm schedule)
  gemm256_ce<<<dim3(500), 512, 0, stream>>>(hid, lmt, ids, PMAX, PSUM, PARGI, PTGT);

  ce_combine<<<256, 256, 0, stream>>>(PMAX, PSUM, PARGI, PTGT, ids, rowbuf);
  final_reduce<<<1, 256, 0, stream>>>(rowbuf, lmask, out);
}

// Round 13
// 439.603 us; speedup vs baseline: 1.2428x; 1.1247x over previous
//
#include <hip/hip_runtime.h>

typedef unsigned int uint32;
typedef unsigned short u16;
typedef __attribute__((ext_vector_type(8))) short bf16x8;
typedef __attribute__((ext_vector_type(4))) float f32x4;

// ---------- helpers ----------
__device__ __forceinline__ u16 f2b(float f) {            // fp32 -> bf16 RNE
  uint32 u = __float_as_uint(f);
  u = (u + 0x7fffu + ((u >> 16) & 1u)) >> 16;
  return (u16)u;
}
__device__ __forceinline__ float b2f(u16 h) {
  return __uint_as_float(((uint32)h) << 16);
}
__device__ __forceinline__ void gl_lds16(const void* g, void* l) {
  typedef const __attribute__((address_space(1))) void* gp_t;
  typedef __attribute__((address_space(3))) void* lp_t;
  __builtin_amdgcn_global_load_lds((gp_t)g, (lp_t)l, 16, 0, 0);
}

// ---------- model constants ----------
#define L 1024
#define D 2048
#define NH 16
#define HD 128
#define VOCAB 32000
#define KV 2048
#define MASK_ID 31999

// ---------- ws layout (bytes) ----------
static constexpr long OFF_KV  = 0;                       // 2048*2048*2
static constexpr long OFF_WTQ = OFF_KV  + 8388608;
static constexpr long OFF_WTK = OFF_WTQ + 8388608;       // contiguous after WTQ (merged QKV GEMM)
static constexpr long OFF_WTV = OFF_WTK + 8388608;
static constexpr long OFF_WTO = OFF_WTV + 8388608;
static constexpr long OFF_Q   = OFF_WTO + 8388608;       // 1024*2048*2
static constexpr long OFF_K   = OFF_Q   + 4194304;       // 2048*2048*2
static constexpr long OFF_VT  = OFF_K   + 8388608;       // 2048*2048*2 (feature x token)
static constexpr long OFF_CTX = OFF_VT  + 8388608;       // 1024*2048*2
static constexpr long OFF_HID = OFF_CTX + 4194304;       // 1024*2048*2
static constexpr long OFF_LMT = OFF_HID + 4194304;       // 32000*2048*2
static constexpr long OFF_PM  = OFF_LMT + 131072000;     // 1024*128*4
static constexpr long OFF_PS  = OFF_PM  + 524288;
static constexpr long OFF_PI  = OFF_PS  + 524288;
static constexpr long OFF_PT  = OFF_PI  + 524288;        // 1024*4
static constexpr long OFF_ROW = OFF_PT  + 4096;          // 1024*2*4
static constexpr long WS_NEED = OFF_ROW + 8192;

// ---------- 128x128 transpose+convert tile body (512 threads, LDS passed in) ----------
__device__ __forceinline__ void transpose128(float* tile, const float* __restrict__ W,
                                             u16* __restrict__ WT,
                                             int Kd, int Nd, int k0, int n0) {
  int t = threadIdx.x;
  int r = t >> 2, cq = (t & 3) * 4;
#pragma unroll
  for (int p = 0; p < 8; ++p) {
    int c = cq + p * 16;
    float4 v = *(const float4*)(W + (long)(k0 + r) * Nd + n0 + c);
    float* d = tile + r * 129 + c;
    d[0] = v.x; d[1] = v.y; d[2] = v.z; d[3] = v.w;
  }
  __syncthreads();
  int q = t & 15, nn0 = t >> 4;   // nn0 0..31
#pragma unroll
  for (int p = 0; p < 4; ++p) {
    int nn = nn0 + p * 32;
    union { u16 v[8]; bf16x8 b; } u;
#pragma unroll
    for (int j = 0; j < 8; ++j) u.v[j] = f2b(tile[(q * 8 + j) * 129 + nn]);
    *(bf16x8*)(WT + (long)(n0 + nn) * Kd + k0 + q * 8) = u.b;
  }
}

// ---------- mega1: prep_kv + transpose of Wq/Wk/Wv/Wo (512 threads) ----------
__global__ __launch_bounds__(512) void mega1(const float* __restrict__ hs,
                                             const int* __restrict__ ids,
                                             const float* __restrict__ emb,
                                             u16* __restrict__ kv,
                                             const float* __restrict__ Wq, const float* __restrict__ Wk,
                                             const float* __restrict__ Wv, const float* __restrict__ Wo,
                                             u16* __restrict__ wtq, u16* __restrict__ wtk,
                                             u16* __restrict__ wtv, u16* __restrict__ wto) {
  __shared__ float tile[128 * 129];
  int bid = blockIdx.x;
  int t = threadIdx.x;
  if (bid < 512) {
    // prep: 4 rows per block
    int r = bid * 4 + (t >> 7);
    int c0 = (t & 127) * 16;
    const float* src;
    if (r < L) {
      src = hs + (long)r * D;
    } else {
      int p = r - L;
      int id = ((p & 15) == 0) ? ids[p] : MASK_ID;
      src = emb + (long)id * D;
    }
    u16* dst = kv + (long)r * D + c0;
#pragma unroll
    for (int qy = 0; qy < 2; ++qy) {
      float4 a = *(const float4*)(src + c0 + qy * 8);
      float4 b = *(const float4*)(src + c0 + qy * 8 + 4);
      ushort4 o0, o1;
      o0.x = f2b(a.x); o0.y = f2b(a.y); o0.z = f2b(a.z); o0.w = f2b(a.w);
      o1.x = f2b(b.x); o1.y = f2b(b.y); o1.z = f2b(b.z); o1.w = f2b(b.w);
      *(ushort4*)(dst + qy * 8) = o0;
      *(ushort4*)(dst + qy * 8 + 4) = o1;
    }
  } else {
    int idx = bid - 512;
    int z = idx >> 8, tt = idx & 255;
    const float* W = (z == 0) ? Wq : (z == 1) ? Wk : (z == 2) ? Wv : Wo;
    u16* T = (z == 0) ? wtq : (z == 1) ? wtk : (z == 2) ? wtv : wto;
    transpose128(tile, W, T, D, D, (tt >> 4) * 128, (tt & 15) * 128);
  }
}

// ---------- 128x128 MFMA GEMM (2-phase), A [M][K] bf16, BT [N][K] bf16 ----------
#define EPI_PLAIN 0
#define EPI_QKV 3
#define EPI_CE 4

template <int EPI>
__global__ __launch_bounds__(256) void gemm128(const u16* __restrict__ A, int lda, long aHead,
                                               const u16* __restrict__ BT, int ldb, long bHead,
                                               u16* __restrict__ C, int ldc, long cHead,
                                               int Kd) {
  __shared__ __align__(16) char lds[16384];
  char* a_lds = lds;
  char* b_lds = lds + 8192;
  int tid = threadIdx.x;
  int lane = tid & 63;
  int wave = tid >> 6;
  int wr = wave >> 1, wc = wave & 1;
  int h = blockIdx.z;
  long tm = (long)blockIdx.x * 128;
  long tn = (long)blockIdx.y * 128;
  const u16* Ap = A + (long)h * aHead + tm * lda;
  const u16* Bp = BT + (long)h * bHead + tn * ldb;

  int soff = tid * 16;
  int srow = soff >> 6;
  int scol = (soff & 63) >> 1;
  char* aldsb = a_lds + wave * 1024;
  char* bldsb = b_lds + wave * 1024;

  f32x4 acc[4][4];
#pragma unroll
  for (int i = 0; i < 4; ++i)
#pragma unroll
    for (int j = 0; j < 4; ++j) acc[i][j] = (f32x4){0.f, 0.f, 0.f, 0.f};

  for (int k0 = 0; k0 < Kd; k0 += 32) {
#pragma unroll
    for (int r = 0; r < 2; ++r) {
      gl_lds16(Ap + (long)(srow + r * 64) * lda + k0 + scol, aldsb + r * 4096);
      gl_lds16(Bp + (long)(srow + r * 64) * ldb + k0 + scol, bldsb + r * 4096);
    }
    __syncthreads();
    bf16x8 af[4], bfr[4];
    int ka = (lane >> 4) << 4;
#pragma unroll
    for (int mi = 0; mi < 4; ++mi)
      af[mi] = *(const bf16x8*)(a_lds + (wr * 64 + mi * 16 + (lane & 15)) * 64 + ka);
#pragma unroll
    for (int ni = 0; ni < 4; ++ni)
      bfr[ni] = *(const bf16x8*)(b_lds + (wc * 64 + ni * 16 + (lane & 15)) * 64 + ka);
#pragma unroll
    for (int mi = 0; mi < 4; ++mi)
#pragma unroll
      for (int ni = 0; ni < 4; ++ni)
        acc[mi][ni] = __builtin_amdgcn_mfma_f32_16x16x32_bf16(af[mi], bfr[ni], acc[mi][ni], 0, 0, 0);
    __syncthreads();
  }

  long crow0 = tm + wr * 64 + ((lane >> 4) << 2);
  int ccol0 = wc * 64 + (lane & 15);
  u16* Cp = C + (long)h * cHead;
#pragma unroll
  for (int mi = 0; mi < 4; ++mi) {
#pragma unroll
    for (int ni = 0; ni < 4; ++ni) {
      long col = tn + ccol0 + ni * 16;
#pragma unroll
      for (int j = 0; j < 4; ++j) {
        long row = crow0 + mi * 16 + j;
        Cp[row * ldc + col] = f2b(acc[mi][ni][j]);
      }
    }
  }
}

// ---------- 256x256 8-phase MFMA GEMM body (T1..T5 + hoisted addressing) ----------
// A [M][K] bf16, BT [N][K] bf16, lda==ldb required (both D here).
template <int EPI>
__device__ __forceinline__ void gemm256_body(char* lds, int wg,
                                             const u16* __restrict__ A, int lda,
                                             const u16* __restrict__ BT,
                                             int Kd, int mtiles,
                                             u16* __restrict__ Cq, u16* __restrict__ Ck,
                                             u16* __restrict__ Cv,
                                             const int* __restrict__ ids,
                                             float* __restrict__ PMAX, float* __restrict__ PSUM,
                                             int* __restrict__ PARGI, float* __restrict__ PTGT) {
  int tm, tn;
  if (EPI == EPI_QKV) {
    if (wg < 32) { tn = wg >> 2; tm = 4 + (wg & 3); }
    else { int e = wg - 32; tn = 8 + (e >> 3); tm = e & 7; }
  } else {
    tm = wg % mtiles; tn = wg / mtiles;
  }

  int tid = threadIdx.x, lane = tid & 63, w = tid >> 6;
  int wm = w >> 2, wn = w & 3;
  int lq = lane & 15, qq = lane >> 4;
  const char* Ap = (const char*)(A + (long)tm * 256 * lda);
  const char* Bp = (const char*)(BT + (long)tn * 256 * lda);
  int NT = Kd >> 6;             // K-tiles of 64; even, >= 2
  int maxs = NT << 2;

  // ---- hoisted addressing ----
  // swizzle term (rr>>1)&3 == (lq>>1)&3 for all fragment rows
  int swz = qq ^ ((lq >> 1) & 3);
  char* pA0 = lds + ((wm * 128 + lq) * 64 + (swz << 4));
  char* pA1 = pA0 + 65536;
  char* pB0 = lds + 32768 + ((wn * 64 + lq) * 64 + (swz << 4));
  char* pB1 = pB0 + 65536;
  int voff[2], lof[2];
#pragma unroll
  for (int l = 0; l < 2; ++l) {
    int o = tid * 16 + l * 8192;
    int rr = o >> 6;
    int ch = (o >> 4) & 3;
    int clog = ch ^ ((rr >> 1) & 3);
    voff[l] = (rr * lda + clog * 8) * 2;   // bytes into source panel
    lof[l] = w * 1024 + l * 8192;          // wave-uniform LDS dest offset
  }

  auto STAGE_SLOT = [&](int s) {
    if (s >= maxs) return;
    int tau = s >> 2, hh = s & 3;
    int kind = (hh & 1) ^ 1;    // 0 = A, 1 = B
    int ks = hh >> 1;
    const char* src = kind ? Bp : Ap;
    long kb = (long)tau * 128 + ks * 64;   // bytes
    char* dstb = lds + (tau & 1) * 65536 + kind * 32768 + ks * 16384;
#pragma unroll
    for (int l = 0; l < 2; ++l)
      gl_lds16(src + kb + voff[l], dstb + lof[l]);
  };

  f32x4 acc[8][4];
#pragma unroll
  for (int i = 0; i < 8; ++i)
#pragma unroll
    for (int j = 0; j < 4; ++j) acc[i][j] = (f32x4){0.f, 0.f, 0.f, 0.f};

  STAGE_SLOT(0); STAGE_SLOT(1); STAGE_SLOT(2); STAGE_SLOT(3);
  asm volatile("s_waitcnt vmcnt(4)" ::: "memory");
  STAGE_SLOT(4); STAGE_SLOT(5); STAGE_SLOT(6);
  asm volatile("s_waitcnt vmcnt(6)" ::: "memory");
  __builtin_amdgcn_s_barrier();
  __builtin_amdgcn_sched_barrier(0);

  bf16x8 bfr[4];

#define G256_PHASE(PA, PB, KS, MH, SLOT, WAITV)                                \
  {                                                                            \
    bf16x8 af[4];                                                              \
    if (MH == 0) {                                                             \
      bfr[0] = *(const bf16x8*)((PB) + (KS) * 16384 + 0 * 1024);               \
      bfr[1] = *(const bf16x8*)((PB) + (KS) * 16384 + 1 * 1024);               \
      bfr[2] = *(const bf16x8*)((PB) + (KS) * 16384 + 2 * 1024);               \
      bfr[3] = *(const bf16x8*)((PB) + (KS) * 16384 + 3 * 1024);               \
    }                                                                          \
    af[0] = *(const bf16x8*)((PA) + (KS) * 16384 + (MH * 4 + 0) * 1024);       \
    af[1] = *(const bf16x8*)((PA) + (KS) * 16384 + (MH * 4 + 1) * 1024);       \
    af[2] = *(const bf16x8*)((PA) + (KS) * 16384 + (MH * 4 + 2) * 1024);       \
    af[3] = *(const bf16x8*)((PA) + (KS) * 16384 + (MH * 4 + 3) * 1024);       \
    STAGE_SLOT(SLOT);                                                          \
    __builtin_amdgcn_sched_barrier(0);                                         \
    __builtin_amdgcn_s_barrier();                                              \
    asm volatile("s_waitcnt lgkmcnt(0)" ::: "memory");                         \
    __builtin_amdgcn_sched_barrier(0);                                         \
    __builtin_amdgcn_s_setprio(1);                                             \
    _Pragma("unroll")                                                          \
    for (int mi2 = 0; mi2 < 4; ++mi2)                                          \
      _Pragma("unroll")                                                        \
      for (int ni = 0; ni < 4; ++ni)                                           \
        acc[MH * 4 + mi2][ni] = __builtin_amdgcn_mfma_f32_16x16x32_bf16(       \
            af[mi2], bfr[ni], acc[MH * 4 + mi2][ni], 0, 0, 0);                 \
    __builtin_amdgcn_s_setprio(0);                                             \
    __builtin_amdgcn_sched_barrier(0);                                         \
    if (WAITV == 6) asm volatile("s_waitcnt vmcnt(6)" ::: "memory");           \
    else if (WAITV == 0) asm volatile("s_waitcnt vmcnt(0)" ::: "memory");      \
    __builtin_amdgcn_s_barrier();                                              \
    __builtin_amdgcn_sched_barrier(0);                                         \
  }

  for (int t = 0; t < NT; t += 2) {
    int s0 = 4 * t;
    int w4 = (t + 2 >= NT) ? 0 : 6;
    G256_PHASE(pA0, pB0, 0, 0, s0 + 7,  -1)
    G256_PHASE(pA0, pB0, 0, 1, s0 + 8,  -1)
    G256_PHASE(pA0, pB0, 1, 0, s0 + 9,  -1)
    G256_PHASE(pA0, pB0, 1, 1, s0 + 10, w4)
    G256_PHASE(pA1, pB1, 0, 0, s0 + 11, -1)
    G256_PHASE(pA1, pB1, 0, 1, s0 + 12, -1)
    G256_PHASE(pA1, pB1, 1, 0, s0 + 13, -1)
    G256_PHASE(pA1, pB1, 1, 1, s0 + 14, 6)
  }
#undef G256_PHASE

  if (EPI == EPI_CE) {
    __syncthreads();
    float* smax = (float*)lds;            // [256][4]
    float* ssum = smax + 1024;
    int* sargi = (int*)(ssum + 1024);
#pragma unroll
    for (int mi = 0; mi < 8; ++mi) {
#pragma unroll
      for (int j = 0; j < 4; ++j) {
        int lrow = mi * 16 + qq * 4 + j;
        long grow = (long)tm * 256 + wm * 128 + lrow;
        int tgt = ids[grow];
        float v[4];
        float mx = -1e30f; int ai = 0;
#pragma unroll
        for (int ni = 0; ni < 4; ++ni) {
          v[ni] = acc[mi][ni][j];
          int col = tn * 256 + wn * 64 + ni * 16 + lq;
          if (col == tgt) PTGT[grow] = v[ni];
          if (v[ni] > mx) { mx = v[ni]; ai = col; }
        }
#pragma unroll
        for (int off = 1; off < 16; off <<= 1) {
          float om = __shfl_xor(mx, off);
          int oa = __shfl_xor(ai, off);
          if (om > mx || (om == mx && oa < ai)) { mx = om; ai = oa; }
        }
        float se = 0.f;
#pragma unroll
        for (int ni = 0; ni < 4; ++ni) se += __expf(v[ni] - mx);
#pragma unroll
        for (int off = 1; off < 16; off <<= 1) se += __shfl_xor(se, off);
        if (lq == 0) {
          int f = wm * 128 + lrow;
          smax[f * 4 + wn] = mx;
          ssum[f * 4 + wn] = se;
          sargi[f * 4 + wn] = ai;
        }
      }
    }
    __syncthreads();
    if (lane < 32) {
      int f = w * 32 + lane;
      float m_t = smax[f * 4]; int a_t = sargi[f * 4];
#pragma unroll
      for (int x = 1; x < 4; ++x) {
        float om = smax[f * 4 + x]; int oa = sargi[f * 4 + x];
        if (om > m_t || (om == m_t && oa < a_t)) { m_t = om; a_t = oa; }
      }
      float s_t = 0.f;
#pragma unroll
      for (int x = 0; x < 4; ++x) s_t += ssum[f * 4 + x] * __expf(smax[f * 4 + x] - m_t);
      long grow = (long)tm * 256 + f;
      PMAX[grow * 128 + tn] = m_t;
      PSUM[grow * 128 + tn] = s_t;
      PARGI[grow * 128 + tn] = a_t;
    }
    return;
  }

  // EPI_QKV store
  long crow = (long)tm * 256 + wm * 128 + ((lane >> 4) << 2);
  long ccol = (long)tn * 256 + wn * 64 + lq;
#pragma unroll
  for (int mi = 0; mi < 8; ++mi)
#pragma unroll
    for (int ni = 0; ni < 4; ++ni)
#pragma unroll
      for (int j = 0; j < 4; ++j) {
        long row = crow + mi * 16 + j;
        long col = ccol + ni * 16;
        u16 val = f2b(acc[mi][ni][j]);
        if (col < 2048) {
          if (row >= 1024) Cq[(row - 1024) * D + col] = val;
        } else if (col < 4096) {
          Ck[row * D + (col - 2048)] = val;
        } else {
          Cv[(col - 4096) * KV + row] = val;
        }
      }
}

// ---------- mega2: QKV gemm256 (blocks 0..159) + lm-head transpose (blocks 160..511) ----------
__global__ __launch_bounds__(512, 2) void mega2(const u16* __restrict__ kv,
                                                const u16* __restrict__ wtq,
                                                u16* __restrict__ qb, u16* __restrict__ kb,
                                                u16* __restrict__ vt,
                                                const float* __restrict__ Wlm,
                                                u16* __restrict__ lmt) {
  __shared__ __align__(16) char lds[131072];
  int bid = blockIdx.x;
  if (bid < 160) {
    // bijective XCD swizzle over 160 (160 % 8 == 0)
    int wg = (bid & 7) * 20 + (bid >> 3);
    gemm256_body<EPI_QKV>(lds, wg, kv, D, wtq, D, 0, qb, kb, vt,
                          nullptr, nullptr, nullptr, nullptr, nullptr);
  } else {
    for (int tile = bid - 160; tile < 4000; tile += 352) {
      int n0 = (tile % 250) * 128;
      int k0 = (tile / 250) * 128;
      transpose128((float*)lds, Wlm, lmt, D, VOCAB, k0, n0);
      __syncthreads();
    }
  }
}

// ---------- lm logits + fused CE partials ----------
__global__ __launch_bounds__(512, 2) void gemm256_ce(const u16* __restrict__ A,
                                                     const u16* __restrict__ BT,
                                                     const int* __restrict__ ids,
                                                     float* __restrict__ PMAX, float* __restrict__ PSUM,
                                                     int* __restrict__ PARGI, float* __restrict__ PTGT) {
  __shared__ __align__(16) char lds[131072];
  int nwg = gridDim.x;
  int orig = blockIdx.x;
  int q8 = nwg >> 3, r8 = nwg & 7;
  int xcd = orig & 7, idx = orig >> 3;
  int wg = (xcd < r8 ? xcd * (q8 + 1) : r8 * (q8 + 1) + (xcd - r8) * q8) + idx;
  gemm256_body<EPI_CE>(lds, wg, A, D, BT, D, 4, nullptr, nullptr, nullptr,
                       ids, PMAX, PSUM, PARGI, PTGT);
}

// ---------- combine CE partials across 125 column tiles ----------
__global__ __launch_bounds__(256) void ce_combine(const float* __restrict__ PMAX,
                                                  const float* __restrict__ PSUM,
                                                  const int* __restrict__ PARGI,
                                                  const float* __restrict__ PTGT,
                                                  const int* __restrict__ ids,
                                                  float* __restrict__ rowbuf) {
  int row = blockIdx.x * 4 + (threadIdx.x >> 6);
  int lane = threadIdx.x & 63;
  const float* pm = PMAX + (long)row * 128;
  const float* ps = PSUM + (long)row * 128;
  const int* pi = PARGI + (long)row * 128;
  float m0 = (lane < 125) ? pm[lane] : -1e30f;
  int a0 = (lane < 125) ? pi[lane] : (1 << 30);
  float m1 = (lane + 64 < 125) ? pm[lane + 64] : -1e30f;
  int a1 = (lane + 64 < 125) ? pi[lane + 64] : (1 << 30);
  float mg = m0; int ag = a0;
  if (m1 > mg || (m1 == mg && a1 < ag)) { mg = m1; ag = a1; }
  for (int off = 1; off < 64; off <<= 1) {
    float om = __shfl_xor(mg, off);
    int oa = __shfl_xor(ag, off);
    if (om > mg || (om == mg && oa < ag)) { mg = om; ag = oa; }
  }
  float s = 0.f;
  if (lane < 125) s += ps[lane] * __expf(m0 - mg);
  if (lane + 64 < 125) s += ps[lane + 64] * __expf(m1 - mg);
  for (int off = 1; off < 64; off <<= 1) s += __shfl_xor(s, off);
  if (lane == 0) {
    rowbuf[row * 2] = mg + logf(s) - PTGT[row];
    rowbuf[row * 2 + 1] = (ag == ids[row]) ? 1.f : 0.f;
  }
}

// ---------- fused flash attention ----------
__global__ __launch_bounds__(256) void flash_attn(const u16* __restrict__ qb,
                                                  const u16* __restrict__ kb,
                                                  const u16* __restrict__ vt,
                                                  u16* __restrict__ ctx) {
  int tid = threadIdx.x;
  int lane = tid & 63;
  int wid = blockIdx.x * 4 + (tid >> 6);   // 0..1023
  int pairid = wid >> 1;
  int h = pairid >> 5;
  int pr = pairid & 31;
  int rb = (wid & 1) ? (63 - pr) : pr;     // balanced load
  int lq = lane & 15;
  int g = lane >> 4;
  const float scale = 0.08838834764831845f;  // 1/sqrt(128)

  const u16* qrow = qb + (long)(rb * 16 + lq) * D + h * HD + g * 8;
  bf16x8 qf[4];
#pragma unroll
  for (int c = 0; c < 4; ++c) qf[c] = *(const bf16x8*)(qrow + c * 32);

  f32x4 o[8];
#pragma unroll
  for (int i = 0; i < 8; ++i) o[i] = (f32x4){0.f, 0.f, 0.f, 0.f};
  float m = -1e30f, lsum = 0.f;

  int nb = rb + 1;
  for (int bp = 0; bp < nb; bp += 2) {
    bool validB = (bp + 1) < nb;
    int tokA = (bp < rb) ? bp * 16 : 1024 + rb * 16;
    int bB = bp + 1;
    int tokB = validB ? ((bB < rb) ? bB * 16 : 1024 + rb * 16) : tokA;

    f32x4 sA = (f32x4){0.f, 0.f, 0.f, 0.f};
    f32x4 sB = (f32x4){0.f, 0.f, 0.f, 0.f};
    const u16* ka = kb + (long)(tokA + lq) * D + h * HD + g * 8;
#pragma unroll
    for (int c = 0; c < 4; ++c) {
      bf16x8 kf = *(const bf16x8*)(ka + c * 32);
      sA = __builtin_amdgcn_mfma_f32_16x16x32_bf16(kf, qf[c], sA, 0, 0, 0);
    }
    if (validB) {
      const u16* kbp = kb + (long)(tokB + lq) * D + h * HD + g * 8;
#pragma unroll
      for (int c = 0; c < 4; ++c) {
        bf16x8 kf = *(const bf16x8*)(kbp + c * 32);
        sB = __builtin_amdgcn_mfma_f32_16x16x32_bf16(kf, qf[c], sB, 0, 0, 0);
      }
    }

    float s8[8];
#pragma unroll
    for (int j = 0; j < 4; ++j) s8[j] = sA[j] * scale;
#pragma unroll
    for (int j = 0; j < 4; ++j) s8[4 + j] = validB ? sB[j] * scale : -1e30f;
    float mx = s8[0];
#pragma unroll
    for (int j = 1; j < 8; ++j) mx = fmaxf(mx, s8[j]);
    mx = fmaxf(mx, __shfl_xor(mx, 16));
    mx = fmaxf(mx, __shfl_xor(mx, 32));
    float mn = fmaxf(m, mx);
    float sc_f = __expf(m - mn);
    m = mn;
    float p[8], ps = 0.f;
#pragma unroll
    for (int j = 0; j < 8; ++j) { p[j] = __expf(s8[j] - mn); ps += p[j]; }
    ps += __shfl_xor(ps, 16);
    ps += __shfl_xor(ps, 32);
    lsum = lsum * sc_f + ps;

    uint32 Aw0 = (uint32)f2b(p[0]) | ((uint32)f2b(p[1]) << 16);
    uint32 Aw1 = (uint32)f2b(p[2]) | ((uint32)f2b(p[3]) << 16);
    uint32 Bw0 = (uint32)f2b(p[4]) | ((uint32)f2b(p[5]) << 16);
    uint32 Bw1 = (uint32)f2b(p[6]) | ((uint32)f2b(p[7]) << 16);
    int s0 = (((2 * g) & 3) << 4) + lq;
    int s1 = (((2 * g + 1) & 3) << 4) + lq;
    uint32 a00 = (uint32)__shfl((int)Aw0, s0), a01 = (uint32)__shfl((int)Aw1, s0);
    uint32 a10 = (uint32)__shfl((int)Aw0, s1), a11 = (uint32)__shfl((int)Aw1, s1);
    uint32 b00 = (uint32)__shfl((int)Bw0, s0), b01 = (uint32)__shfl((int)Bw1, s0);
    uint32 b10 = (uint32)__shfl((int)Bw0, s1), b11 = (uint32)__shfl((int)Bw1, s1);
    union { uint32 u[4]; bf16x8 v; } pu;
    pu.u[0] = (g < 2) ? a00 : b00;
    pu.u[1] = (g < 2) ? a01 : b01;
    pu.u[2] = (g < 2) ? a10 : b10;
    pu.u[3] = (g < 2) ? a11 : b11;

#pragma unroll
    for (int nt = 0; nt < 8; ++nt)
#pragma unroll
      for (int j = 0; j < 4; ++j) o[nt][j] *= sc_f;
    int tok_g = (g < 2) ? (tokA + g * 8) : (tokB + (g - 2) * 8);
    const u16* vrow = vt + (long)(h * HD + lq) * KV + tok_g;
#pragma unroll
    for (int nt = 0; nt < 8; ++nt) {
      bf16x8 vf = *(const bf16x8*)(vrow + (long)nt * 16 * KV);
      o[nt] = __builtin_amdgcn_mfma_f32_16x16x32_bf16(vf, pu.v, o[nt], 0, 0, 0);
    }
  }

  float inv = 1.f / lsum;
  u16* cp = ctx + (long)(rb * 16 + lq) * D + h * HD + g * 4;
#pragma unroll
  for (int nt = 0; nt < 8; ++nt) {
    ushort4 st;
    st.x = f2b(o[nt][0] * inv); st.y = f2b(o[nt][1] * inv);
    st.z = f2b(o[nt][2] * inv); st.w = f2b(o[nt][3] * inv);
    *(ushort4*)(cp + nt * 16) = st;
  }
}

// ---------- final: masked mean loss + accuracy ----------
__global__ __launch_bounds__(256) void final_reduce(const float* __restrict__ rowbuf,
                                                    const float* __restrict__ loss_mask,
                                                    float* __restrict__ out) {
  int t = threadIdx.x;
  float ce = 0.f, cnt = 0.f, cor = 0.f;
  for (int r = t; r < L; r += 256) {
    bool valid = (r >= 16) && ((r & 15) != 0);
    float comb = loss_mask[r] * (valid ? 1.f : 0.f);
    if (comb > 1e-6f) {
      ce += rowbuf[r * 2];
      cor += rowbuf[r * 2 + 1];
      cnt += 1.f;
    }
  }
  for (int off = 1; off < 64; off <<= 1) {
    ce += __shfl_xor(ce, off);
    cnt += __shfl_xor(cnt, off);
    cor += __shfl_xor(cor, off);
  }
  __shared__ float s1[4], s2[4], s3[4];
  int lane = t & 63, w = t >> 6;
  if (lane == 0) { s1[w] = ce; s2[w] = cnt; s3[w] = cor; }
  __syncthreads();
  if (t == 0) {
    float C = s1[0] + s1[1] + s1[2] + s1[3];
    float N = s2[0] + s2[1] + s2[2] + s2[3];
    float R = s3[0] + s3[1] + s3[2] + s3[3];
    out[0] = C / N;
    out[1] = R / N;
  }
}

__global__ void ws_too_small(float* out, float mb) {
  if (threadIdx.x == 0) { out[0] = 1e6f + mb; out[1] = -1e6f; }
}

// ---------- launch ----------
extern "C" void kernel_launch(void* const* d_in, const int* in_sizes, int n_in,
                              void* d_out, int out_size, void* d_ws, size_t ws_size,
                              hipStream_t stream) {
  const int* ids = (const int*)d_in[0];
  const float* hs = (const float*)d_in[2];
  const float* lmask = (const float*)d_in[3];
  const float* emb = (const float*)d_in[4];
  const float* Wq = (const float*)d_in[5];
  const float* Wk = (const float*)d_in[6];
  const float* Wv = (const float*)d_in[7];
  const float* Wo = (const float*)d_in[8];
  const float* Wlm = (const float*)d_in[9];
  float* out = (float*)d_out;
  char* ws = (char*)d_ws;

  if (ws_size < (size_t)WS_NEED) {
    ws_too_small<<<1, 64, 0, stream>>>(out, (float)(ws_size >> 20));
    return;
  }

  u16* kv  = (u16*)(ws + OFF_KV);
  u16* wtq = (u16*)(ws + OFF_WTQ);
  u16* wtk = (u16*)(ws + OFF_WTK);
  u16* wtv = (u16*)(ws + OFF_WTV);
  u16* wto = (u16*)(ws + OFF_WTO);
  u16* qb  = (u16*)(ws + OFF_Q);
  u16* kb  = (u16*)(ws + OFF_K);
  u16* vt  = (u16*)(ws + OFF_VT);
  u16* ctx = (u16*)(ws + OFF_CTX);
  u16* hid = (u16*)(ws + OFF_HID);
  u16* lmt = (u16*)(ws + OFF_LMT);
  float* PMAX = (float*)(ws + OFF_PM);
  float* PSUM = (float*)(ws + OFF_PS);
  int* PARGI = (int*)(ws + OFF_PI);
  float* PTGT = (float*)(ws + OFF_PT);
  float* rowbuf = (float*)(ws + OFF_ROW);

  // prep kv + transpose Wq/Wk/Wv/Wo
  mega1<<<dim3(1536), 512, 0, stream>>>(hs, ids, emb, kv, Wq, Wk, Wv, Wo,
                                        wtq, wtk, wtv, wto);
  // QKV projection (8-phase 256^2) overlapped with lm-head transpose
  mega2<<<dim3(512), 512, 0, stream>>>(kv, wtq, qb, kb, vt, Wlm, lmt);

  // fused block-masked flash attention -> ctx
  flash_attn<<<dim3(256), 256, 0, stream>>>(qb, kb, vt, ctx);

  // hidden = ctx @ Wo
  gemm128<EPI_PLAIN><<<dim3(8, 16, 1), 256, 0, stream>>>(ctx, D, 0, wto, D, 0, hid, D, 0, D);

  // logits + fused CE partials (no logit materialization)
  gemm256_ce<<<dim3(500), 512, 0, stream>>>(hid, lmt, ids, PMAX, PSUM, PARGI, PTGT);

  ce_combine<<<256, 256, 0, stream>>>(PMAX, PSUM, PARGI, PTGT, ids, rowbuf);
  final_reduce<<<1, 256, 0, stream>>>(rowbuf, lmask, out);
}